// Round 3
// baseline (443.295 us; speedup 1.0000x reference)
//
#include <hip/hip_runtime.h>

typedef __bf16 bf16;
typedef __bf16 bf16x4 __attribute__((ext_vector_type(4)));
typedef __bf16 bf16x8 __attribute__((ext_vector_type(8)));
typedef float f32x4 __attribute__((ext_vector_type(4)));

#define MFMA16(a, b, c) __builtin_amdgcn_mfma_f32_16x16x32_bf16(a, b, c, 0, 0, 0)

// Problem constants: B=8, N=4096, M=256, DIM=256, HEADS=8, DIM_HEAD=64, INNER=512
// exp(S*scale) = exp2(S * 0.125 * log2(e))
#define CEXP 0.18033688011112042f

// ---------------------------------------------------------------------------
// Weight pre-transpose + downcast: W[K,N] fp32 -> WT[N,K] bf16 (10 matrices)
// ---------------------------------------------------------------------------
struct WTArgs {
  const float* src[10];
  bf16* dst[10];
  int K[10];
  int N[10];
};

__global__ __launch_bounds__(256) void wtrans_kernel(WTArgs args) {
  const int z = blockIdx.z;
  const int K = args.K[z], N = args.N[z];
  const int k0 = blockIdx.x * 64, n0 = blockIdx.y * 64;
  if (k0 >= K || n0 >= N) return;
  __shared__ float t[64][65];
  const int tx = threadIdx.x & 63, ty = threadIdx.x >> 6;
  const float* __restrict__ src = args.src[z];
  bf16* __restrict__ dst = args.dst[z];
#pragma unroll
  for (int i = 0; i < 16; ++i)
    t[ty + i * 4][tx] = src[(size_t)(k0 + ty + i * 4) * N + n0 + tx];
  __syncthreads();
#pragma unroll
  for (int i = 0; i < 16; ++i)
    dst[(size_t)(n0 + ty + i * 4) * K + k0 + tx] = (bf16)t[tx][ty + i * 4];
}

// ---------------------------------------------------------------------------
// xq[b][n][c] = feat[b][n][c] + pos[b][c][n]  (fp32 in, bf16 out)
// ---------------------------------------------------------------------------
__global__ __launch_bounds__(256) void prep_xq_kernel(
    const float* __restrict__ feat, const float* __restrict__ pos,
    bf16* __restrict__ xq) {
  const int n0 = blockIdx.x * 64;
  const int c0 = blockIdx.y * 64;
  const int b = blockIdx.z;
  __shared__ float t[64][65];
  const int tx = threadIdx.x & 63, ty = threadIdx.x >> 6;
#pragma unroll
  for (int i = 0; i < 16; ++i) {
    int c = ty + i * 4;
    t[c][tx] = pos[((size_t)b * 256 + c0 + c) * 4096 + n0 + tx];
  }
  __syncthreads();
#pragma unroll
  for (int i = 0; i < 16; ++i) {
    int n = ty + i * 4;
    size_t off = ((size_t)b * 4096 + n0 + n) * 256 + c0 + tx;
    xq[off] = (bf16)(feat[off] + t[tx][n]);
  }
}

// xk = center + center_pos (fp32 in, bf16 out, vectorized x4)
__global__ __launch_bounds__(256) void addvec_kernel(
    const float* __restrict__ a, const float* __restrict__ b,
    bf16* __restrict__ o, int n4) {
  int i = blockIdx.x * 256 + threadIdx.x;
  if (i < n4) {
    f32x4 x = ((const f32x4*)a)[i];
    f32x4 y = ((const f32x4*)b)[i];
    bf16x4 z;
#pragma unroll
    for (int j = 0; j < 4; ++j) z[j] = (bf16)(x[j] + y[j]);
    ((bf16x4*)o)[i] = z;
  }
}

// ---------------------------------------------------------------------------
// A-tile load helper: 8 contiguous elements -> bf16x8 (fp32 converts inline)
// ---------------------------------------------------------------------------
template <typename TA>
__device__ inline bf16x8 ldA8(const TA* p);
template <>
__device__ inline bf16x8 ldA8<bf16>(const bf16* p) {
  return *(const bf16x8*)p;
}
template <>
__device__ inline bf16x8 ldA8<float>(const float* p) {
  f32x4 u = *(const f32x4*)p;
  f32x4 v = *((const f32x4*)p + 1);
  bf16x8 o;
#pragma unroll
  for (int i = 0; i < 4; ++i) {
    o[i] = (bf16)u[i];
    o[4 + i] = (bf16)v[i];
  }
  return o;
}

// ---------------------------------------------------------------------------
// Generic GEMM: C[M,N] = A[M,K] @ B[K,N], B pre-transposed BT[N,K] (bf16).
// 128x128 tile, 4 waves (each 64x64), BK=32, single-buffered LDS.
// EPI: 0=none, 1=relu, 2=+resid, 3=+bias+resid. TO out, TR resid, TA a-input.
// ---------------------------------------------------------------------------
template <int EPI, typename TO, typename TR, typename TA>
__global__ __launch_bounds__(256) void gemm_kernel(
    const TA* __restrict__ A, const bf16* __restrict__ BT,
    TO* __restrict__ C, const TR* __restrict__ resid,
    const float* __restrict__ bias, int M, int N, int K) {
  const int m0 = blockIdx.x * 128;
  const int n0 = blockIdx.y * 128;
  const int tid = threadIdx.x;
  const int lane = tid & 63;
  const int w = tid >> 6;
  const int wr = (w >> 1) * 64, wc = (w & 1) * 64;
  const int l15 = lane & 15, quad = lane >> 4;

  __shared__ bf16 Al[128 * 40];  // rows padded 32->40 (80B, 16B-aligned)
  __shared__ bf16 Bl[128 * 40];

  f32x4 acc[4][4];
#pragma unroll
  for (int i = 0; i < 4; ++i)
#pragma unroll
    for (int j = 0; j < 4; ++j) acc[i][j] = (f32x4){0.f, 0.f, 0.f, 0.f};

  for (int k0 = 0; k0 < K; k0 += 32) {
#pragma unroll
    for (int c = 0; c < 2; ++c) {
      int idx = tid + c * 256;          // 0..511
      int row = idx >> 2;               // 0..127
      int ko = (idx & 3) * 8;           // 0,8,16,24
      *(bf16x8*)(Al + row * 40 + ko) =
          ldA8(A + (size_t)(m0 + row) * K + k0 + ko);
      *(bf16x8*)(Bl + row * 40 + ko) =
          *(const bf16x8*)(BT + (size_t)(n0 + row) * K + k0 + ko);
    }
    __syncthreads();
    bf16x8 fa[4], fb[4];
#pragma unroll
    for (int i = 0; i < 4; ++i) {
      fa[i] = *(const bf16x8*)(Al + (wr + i * 16 + l15) * 40 + quad * 8);
      fb[i] = *(const bf16x8*)(Bl + (wc + i * 16 + l15) * 40 + quad * 8);
    }
#pragma unroll
    for (int i = 0; i < 4; ++i)
#pragma unroll
      for (int j = 0; j < 4; ++j)
        acc[i][j] = MFMA16(fa[i], fb[j], acc[i][j]);
    __syncthreads();
  }

#pragma unroll
  for (int i = 0; i < 4; ++i) {
#pragma unroll
    for (int r = 0; r < 4; ++r) {
      int row = m0 + wr + i * 16 + quad * 4 + r;
      size_t rb = (size_t)row * N + n0 + wc;
#pragma unroll
      for (int j = 0; j < 4; ++j) {
        int col = j * 16 + l15;
        float v = acc[i][j][r];
        if constexpr (EPI == 1) v = fmaxf(v, 0.f);
        if constexpr (EPI == 2) v += (float)resid[rb + col];
        if constexpr (EPI == 3)
          v += bias[n0 + wc + col] + (float)resid[rb + col];
        C[rb + col] = (TO)v;
      }
    }
  }
}

// ---------------------------------------------------------------------------
// Fused dual-softmax attention, v3: 8 waves (512 thr), 2 waves/SIMD.
// Grid (nb=4, h=8, b=8): block owns 1024 n-rows of one (b,h); 8 chs of 128.
// LDS (exactly 160KB, all XOR-swizzled: elem ^= (row&7)<<3):
//   klds [256 m][64 d] 32KB  | v2T [64 d][256 m-perm] 32KB
//   v1T[2][64 d][128 n] 32KB | PS [256 m][128 n] 64KB
// Swapped QK^T: s = mfma(K, q) -> lane holds E[m-range][n=own col]. O1's
// A-operand (P rows n, k=m) is then built IN REGISTERS (bf16 cvt only); a
// fixed k-slot permutation pi is applied to v2T columns so A/B k-orders
// agree. PS (E^T, [m][n]) feeds O2 + a ones-MFMA that produces colsum
// (replaces shuffles). Each wave owns m-stripe w*32..w*32+31 for O2 ->
// epilogue is plain stores (atomic-free partials as before).
// 2 barriers per ch. v1 prefetched one ch ahead (global->reg->LDS split);
// q prefetched in phase B.
// NOTE: af aliases q (rows of ch read strictly before af(ch) written; the
// barrier at end of phase B orders cross-wave) -> q/af NOT __restrict__.
// ---------------------------------------------------------------------------
__global__ __launch_bounds__(512, 2) void attf_kernel(
    const bf16* q, const bf16* __restrict__ kk, const bf16* __restrict__ v1,
    const bf16* __restrict__ v2, bf16* af, float* __restrict__ acc_p,
    float* __restrict__ colsum_p) {
  const int nb = blockIdx.x;  // 4 blocks of 1024 rows
  const int h = blockIdx.y;
  const int b = blockIdx.z;
  const int tid = threadIdx.x;  // 0..511
  const int lane = tid & 63;
  const int w = tid >> 6;  // 0..7
  const int l15 = lane & 15, quad = lane >> 4;

  __shared__ __align__(16) bf16 klds[256 * 64];    // 32KB
  __shared__ __align__(16) bf16 v2T[64 * 256];     // 32KB
  __shared__ __align__(16) bf16 v1T[2][64 * 128];  // 32KB
  __shared__ __align__(16) bf16 PS[256 * 128];     // 64KB

  // ---- prologue: stage K, v2T (perm+swz), v1T[0]; load q frags ch=0 ----
#pragma unroll
  for (int c = 0; c < 4; ++c) {
    int idx = tid + c * 512;  // 0..2047
    int m = idx >> 3, dc = (idx & 7) * 8;
    bf16x8 t =
        *(const bf16x8*)(kk + ((size_t)(b * 256 + m)) * 512 + h * 64 + dc);
    *(bf16x8*)(klds + ((m * 64 + dc) ^ ((m & 7) << 3))) = t;
  }
#pragma unroll
  for (int c = 0; c < 4; ++c) {
    int idx = tid + c * 512;
    int m = idx & 255, dc = (idx >> 8) * 8;
    bf16x8 t =
        *(const bf16x8*)(v2 + ((size_t)(b * 256 + m)) * 512 + h * 64 + dc);
    // column perm pi^-1: within 32-block, p = q8*8 + low + hi*4
    int p = (m & ~31) |
            (((((m >> 2) & 3) << 3) + (m & 3)) + (((m >> 4) & 1) << 2));
#pragma unroll
    for (int j = 0; j < 8; ++j) {
      int d = dc + j;
      v2T[(d * 256 + p) ^ ((d & 7) << 3)] = t[j];
    }
  }
  {
    int n = tid & 127, dg = tid >> 7;  // n-major -> conflict-free LDS writes
    const bf16* vp =
        v1 + ((size_t)(b * 4096 + nb * 1024 + n)) * 512 + h * 64 + dg * 8;
    bf16x8 t0 = *(const bf16x8*)(vp);
    bf16x8 t1 = *(const bf16x8*)(vp + 32);
#pragma unroll
    for (int j = 0; j < 8; ++j) {
      int d0 = dg * 8 + j, d1 = d0 + 32;
      v1T[0][(d0 * 128 + n) ^ ((d0 & 7) << 3)] = t0[j];
      v1T[0][(d1 * 128 + n) ^ ((d1 & 7) << 3)] = t1[j];
    }
  }
  bf16x8 qa0, qa1;
  {
    int nrow = b * 4096 + nb * 1024 + w * 16 + l15;
    const bf16* qp = q + (size_t)nrow * 512 + h * 64 + quad * 8;
    qa0 = *(const bf16x8*)(qp);
    qa1 = *(const bf16x8*)(qp + 32);
  }

  f32x4 oc2[8];
#pragma unroll
  for (int i = 0; i < 8; ++i) oc2[i] = (f32x4){0.f, 0.f, 0.f, 0.f};
  f32x4 csa[2];
  csa[0] = (f32x4){0.f, 0.f, 0.f, 0.f};
  csa[1] = (f32x4){0.f, 0.f, 0.f, 0.f};
  bf16x8 ones8;
#pragma unroll
  for (int j = 0; j < 8; ++j) ones8[j] = (bf16)1.0f;
  const int nloc = w * 16 + l15;

  __syncthreads();

  for (int ch = 0; ch < 8; ++ch) {
    // ---------------- phase A: QK^T + O1 + af ----------------
    // v1(ch+1) global->reg prefetch (latency hides under QK/O1)
    bf16x8 v1a, v1b;
    const int vn = tid & 127, vdg = tid >> 7;
    if (ch < 7) {
      const bf16* vp =
          v1 + ((size_t)(b * 4096 + nb * 1024 + (ch + 1) * 128 + vn)) * 512 +
          h * 64 + vdg * 8;
      v1a = *(const bf16x8*)(vp);
      v1b = *(const bf16x8*)(vp + 32);
    }

    bf16x8 pa[8];
    float rs = 0.f;
#pragma unroll
    for (int mt = 0; mt < 16; ++mt) {
      int mrow = mt * 16 + l15;
      int kb = mrow * 64;
      int sw = (mrow & 7) << 3;
      bf16x8 ka = *(const bf16x8*)(klds + ((kb + quad * 8) ^ sw));
      bf16x8 kc = *(const bf16x8*)(klds + ((kb + 32 + quad * 8) ^ sw));
      f32x4 s = (f32x4){0.f, 0.f, 0.f, 0.f};
      s = MFMA16(ka, qa0, s);  // swapped: A=K rows m, B=q cols n
      s = MFMA16(kc, qa1, s);
      float e0 = exp2f(s[0] * CEXP);
      float e1 = exp2f(s[1] * CEXP);
      float e2 = exp2f(s[2] * CEXP);
      float e3 = exp2f(s[3] * CEXP);
      rs += (e0 + e1) + (e2 + e3);
      bf16 b0 = (bf16)e0, b1 = (bf16)e1, b2 = (bf16)e2, b3 = (bf16)e3;
      int m0 = mt * 16 + quad * 4;  // lane's E rows: m0..m0+3, col n=nloc
      PS[((m0 + 0) * 128 + nloc) ^ (((m0 + 0) & 7) << 3)] = b0;
      PS[((m0 + 1) * 128 + nloc) ^ (((m0 + 1) & 7) << 3)] = b1;
      PS[((m0 + 2) * 128 + nloc) ^ (((m0 + 2) & 7) << 3)] = b2;
      PS[((m0 + 3) * 128 + nloc) ^ (((m0 + 3) & 7) << 3)] = b3;
      // pack O1 A-frag in regs; k-slot (quad,jj) holds m = pi(quad,jj)
      pa[mt >> 1][(mt & 1) * 4 + 0] = b0;
      pa[mt >> 1][(mt & 1) * 4 + 1] = b1;
      pa[mt >> 1][(mt & 1) * 4 + 2] = b2;
      pa[mt >> 1][(mt & 1) * 4 + 3] = b3;
    }

    // O1 = P @ v2 (A from regs, B from perm'd v2T; k = m, 8 ksteps)
    f32x4 o1[4];
#pragma unroll
    for (int i = 0; i < 4; ++i) o1[i] = (f32x4){0.f, 0.f, 0.f, 0.f};
#pragma unroll
    for (int ks = 0; ks < 8; ++ks) {
#pragma unroll
      for (int dt = 0; dt < 4; ++dt) {
        int d = dt * 16 + l15;
        bf16x8 vb = *(const bf16x8*)(v2T +
                                     ((d * 256 + ks * 32 + quad * 8) ^
                                      ((d & 7) << 3)));
        o1[dt] = MFMA16(pa[ks], vb, o1[dt]);
      }
    }

    // rowsum (lane-local over m) -> cross-quad reduce -> normalize + write af
    float rsf = rs + __shfl_xor(rs, 16, 64);
    rsf += __shfl_xor(rsf, 32, 64);
#pragma unroll
    for (int r = 0; r < 4; ++r) {
      float iv = 1.f / __shfl(rsf, (lane & 48) | (quad * 4 + r), 64);
      int n = nb * 1024 + ch * 128 + w * 16 + quad * 4 + r;
      bf16* ap = af + ((size_t)(b * 4096 + n)) * 512 + h * 64 + l15;
#pragma unroll
      for (int dt = 0; dt < 4; ++dt)
        ap[dt * 16] = (bf16)(o1[dt][r] * iv);
    }

    // write prefetched v1 into the other buffer
    if (ch < 7) {
      bf16* dst = v1T[(ch + 1) & 1];
#pragma unroll
      for (int j = 0; j < 8; ++j) {
        int d0 = vdg * 8 + j, d1 = d0 + 32;
        dst[(d0 * 128 + vn) ^ ((d0 & 7) << 3)] = v1a[j];
        dst[(d1 * 128 + vn) ^ ((d1 & 7) << 3)] = v1b[j];
      }
    }
    __syncthreads();  // PS + next v1T ready

    // ---------------- phase B: O2 (+colsum via ones-MFMA) ----------------
    bf16x8 qn0 = qa0, qn1 = qa1;
    if (ch < 7) {
      int nrow = b * 4096 + nb * 1024 + (ch + 1) * 128 + w * 16 + l15;
      const bf16* qp = q + (size_t)nrow * 512 + h * 64 + quad * 8;
      qn0 = *(const bf16x8*)(qp);
      qn1 = *(const bf16x8*)(qp + 32);
    }
    const bf16* vc = v1T[ch & 1];
#pragma unroll
    for (int ks = 0; ks < 4; ++ks) {
      bf16x8 vbv[4];
#pragma unroll
      for (int dt = 0; dt < 4; ++dt) {
        int d = dt * 16 + l15;
        vbv[dt] = *(const bf16x8*)(vc + ((d * 128 + ks * 32 + quad * 8) ^
                                         ((d & 7) << 3)));
      }
#pragma unroll
      for (int mr = 0; mr < 2; ++mr) {
        int m = w * 32 + mr * 16 + l15;
        bf16x8 pa2 = *(const bf16x8*)(PS + ((m * 128 + ks * 32 + quad * 8) ^
                                            ((m & 7) << 3)));
#pragma unroll
        for (int dt = 0; dt < 4; ++dt)
          oc2[mr * 4 + dt] = MFMA16(pa2, vbv[dt], oc2[mr * 4 + dt]);
        csa[mr] = MFMA16(pa2, ones8, csa[mr]);  // colsum partial
      }
    }
    __syncthreads();  // WAR: PS/v1T reads done before next ch restage
    qa0 = qn0;
    qa1 = qn1;
  }

  // ---- epilogue: plain stores, wave owns m-stripe w*32..w*32+31 ----
  const size_t slab = (size_t)(nb * 64 + b * 8 + h);
  if (l15 == 0) {
#pragma unroll
    for (int mr = 0; mr < 2; ++mr)
#pragma unroll
      for (int r = 0; r < 4; ++r)
        colsum_p[slab * 256 + w * 32 + mr * 16 + quad * 4 + r] = csa[mr][r];
  }
  float* base = acc_p + slab * (256 * 64);
#pragma unroll
  for (int mr = 0; mr < 2; ++mr)
#pragma unroll
    for (int dt = 0; dt < 4; ++dt)
#pragma unroll
      for (int r = 0; r < 4; ++r)
        base[(w * 32 + mr * 16 + quad * 4 + r) * 64 + dt * 16 + l15] =
            oc2[mr * 4 + dt][r];
}

// ---------------------------------------------------------------------------
// acm[b][m][h*64+d] = sum_p acc_p[p][b][h][m][d] / sum_p colsum_p[p][b][h][m]
// ---------------------------------------------------------------------------
__global__ __launch_bounds__(256) void acm_kernel(
    const float* __restrict__ acc_p, const float* __restrict__ colsum_p,
    bf16* __restrict__ acm) {
  int idx = blockIdx.x * 256 + threadIdx.x;  // 8*256*512 total
  int d = idx & 63;
  int h = (idx >> 6) & 7;
  int m = (idx >> 9) & 255;
  int b = idx >> 17;
  float cv = 0.f, v = 0.f;
#pragma unroll
  for (int p = 0; p < 4; ++p) {
    cv += colsum_p[((size_t)(p * 64 + b * 8 + h)) * 256 + m];
    v += acc_p[(((size_t)(p * 64 + b * 8 + h)) * 256 + m) * 64 + d];
  }
  acm[idx] = (bf16)(v / cv);
}

// ---------------------------------------------------------------------------
// LayerNorm over last dim (256): one wave per row, 4 rows per block.
// ---------------------------------------------------------------------------
__global__ __launch_bounds__(256) void ln_kernel(
    const bf16* __restrict__ x, const float* __restrict__ wv,
    const float* __restrict__ bv, bf16* __restrict__ y, int rows) {
  int wave = threadIdx.x >> 6;
  int lane = threadIdx.x & 63;
  int row = blockIdx.x * 4 + wave;
  if (row >= rows) return;
  const bf16* xr = x + (size_t)row * 256;
  bf16x4 v = *(const bf16x4*)(xr + lane * 4);
  float f0 = v[0], f1 = v[1], f2 = v[2], f3 = v[3];
  float s = f0 + f1 + f2 + f3;
  float ss = f0 * f0 + f1 * f1 + f2 * f2 + f3 * f3;
#pragma unroll
  for (int m = 1; m < 64; m <<= 1) {
    s += __shfl_xor(s, m, 64);
    ss += __shfl_xor(ss, m, 64);
  }
  float mean = s * (1.f / 256.f);
  float var = ss * (1.f / 256.f) - mean * mean;
  float rstd = rsqrtf(var + 1e-5f);
  f32x4 wq = *(const f32x4*)(wv + lane * 4);
  f32x4 bq = *(const f32x4*)(bv + lane * 4);
  bf16x4 o;
  o[0] = (bf16)((f0 - mean) * rstd * wq[0] + bq[0]);
  o[1] = (bf16)((f1 - mean) * rstd * wq[1] + bq[1]);
  o[2] = (bf16)((f2 - mean) * rstd * wq[2] + bq[2]);
  o[3] = (bf16)((f3 - mean) * rstd * wq[3] + bq[3]);
  *(bf16x4*)(y + (size_t)row * 256 + lane * 4) = o;
}

// ---------------------------------------------------------------------------
extern "C" void kernel_launch(void* const* d_in, const int* in_sizes, int n_in,
                              void* d_out, int out_size, void* d_ws,
                              size_t ws_size, hipStream_t stream) {
  const float* feat = (const float*)d_in[0];
  const float* center = (const float*)d_in[1];
  const float* pos = (const float*)d_in[2];
  const float* cpos = (const float*)d_in[3];
  const float* Wq = (const float*)d_in[4];
  const float* Wk = (const float*)d_in[5];
  const float* Wv1 = (const float*)d_in[6];
  const float* Wv2 = (const float*)d_in[7];
  const float* Wo1 = (const float*)d_in[8];
  const float* Wo2 = (const float*)d_in[9];
  const float* ln1w = (const float*)d_in[10];
  const float* ln1b = (const float*)d_in[11];
  const float* ln2w = (const float*)d_in[12];
  const float* ln2b = (const float*)d_in[13];
  const float* f1W1 = (const float*)d_in[14];
  const float* f1W2 = (const float*)d_in[15];
  const float* f1b2 = (const float*)d_in[16];
  const float* f2W1 = (const float*)d_in[17];
  const float* f2W2 = (const float*)d_in[18];
  const float* f2b2 = (const float*)d_in[19];

  char* ws = (char*)d_ws;
  const size_t MB = 1024 * 1024;
  // workspace layout (~94 MB). af aliases q (fused kernel reads q rows before
  // writing the same rows). acc partials alias xq (dead after q GEMM); acm
  // aliases v2 (dead after attf).
  bf16* q_ = (bf16*)(ws + 0);           // 32MB [32768,512]
  bf16* af_ = q_;                       // alias (see attf_kernel note)
  bf16* v1_ = (bf16*)(ws + 32 * MB);    // 32MB [32768,512]
  bf16* xq_ = (bf16*)(ws + 64 * MB);    // 16MB [32768,256]
  float* accp_ = (float*)(ws + 64 * MB);  // alias: 16MB fp32 [4,8,8,256,64]
  bf16* rf_ = xq_;                      // alias after acm (Wo1 GEMM output)
  bf16* k_ = (bf16*)(ws + 80 * MB);     // 2MB [2048,512]
  bf16* xk_ = (bf16*)(ws + 82 * MB);    // 1MB [2048,256]
  bf16* rc_ = xk_;                      // alias
  bf16* v2_ = (bf16*)(ws + 83 * MB);    // 2MB [2048,512]
  bf16* acm_ = v2_;                     // alias after attf
  float* colsum_ = (float*)(ws + 89 * MB);     // 256KB fp32 [4,8,8,256]
  bf16* wt_ = (bf16*)(ws + 89 * MB + 262144);  // 2MB transposed weights
  bf16* yf_ = q_;                       // alias: af dead after Wo1 GEMM
  bf16* tf_ = (bf16*)(ws + 16 * MB);    // upper half of q/af region
  bf16* yc_ = (bf16*)(ws + 92 * MB);    // 1MB
  bf16* tc_ = (bf16*)(ws + 93 * MB);    // 1MB

  bf16* WqT = wt_;
  bf16* WkT = WqT + 131072;
  bf16* Wv1T = WkT + 131072;
  bf16* Wv2T = Wv1T + 131072;
  bf16* Wo1T = Wv2T + 131072;
  bf16* Wo2T = Wo1T + 131072;
  bf16* f1W1T = Wo2T + 131072;
  bf16* f1W2T = f1W1T + 65536;
  bf16* f2W1T = f1W2T + 65536;
  bf16* f2W2T = f2W1T + 65536;

  float* out_feat = (float*)d_out;
  float* out_center = out_feat + (size_t)8 * 4096 * 256;

  WTArgs wa;
  const float* srcs[10] = {Wq, Wk, Wv1, Wv2, Wo1, Wo2, f1W1, f1W2, f2W1, f2W2};
  bf16* dsts[10] = {WqT, WkT, Wv1T, Wv2T, Wo1T, Wo2T, f1W1T, f1W2T, f2W1T, f2W2T};
  int Ks[10] = {256, 256, 256, 256, 512, 512, 256, 256, 256, 256};
  int Ns[10] = {512, 512, 512, 512, 256, 256, 256, 256, 256, 256};
  for (int i = 0; i < 10; ++i) {
    wa.src[i] = srcs[i];
    wa.dst[i] = dsts[i];
    wa.K[i] = Ks[i];
    wa.N[i] = Ns[i];
  }

  wtrans_kernel<<<dim3(8, 8, 10), 256, 0, stream>>>(wa);
  prep_xq_kernel<<<dim3(64, 4, 8), 256, 0, stream>>>(feat, pos, xq_);
  addvec_kernel<<<dim3(512), 256, 0, stream>>>(center, cpos, xk_, 131072);

  // projections (v1/v2 read fp32 inputs directly)
  gemm_kernel<0, bf16, bf16, bf16><<<dim3(256, 4), 256, 0, stream>>>(
      xq_, WqT, q_, nullptr, nullptr, 32768, 512, 256);
  gemm_kernel<0, bf16, bf16, bf16><<<dim3(16, 4), 256, 0, stream>>>(
      xk_, WkT, k_, nullptr, nullptr, 2048, 512, 256);
  gemm_kernel<0, bf16, bf16, float><<<dim3(256, 4), 256, 0, stream>>>(
      feat, Wv1T, v1_, nullptr, nullptr, 32768, 512, 256);
  gemm_kernel<0, bf16, bf16, float><<<dim3(16, 4), 256, 0, stream>>>(
      center, Wv2T, v2_, nullptr, nullptr, 2048, 512, 256);

  // fused dual-softmax attention (atomic-free partials, no memset needed)
  attf_kernel<<<dim3(4, 8, 8), 512, 0, stream>>>(q_, k_, v1_, v2_, af_, accp_,
                                                 colsum_);
  acm_kernel<<<dim3(4096), 256, 0, stream>>>(accp_, colsum_, acm_);

  // feat path
  gemm_kernel<2, bf16, float, bf16><<<dim3(256, 2), 256, 0, stream>>>(
      af_, Wo1T, rf_, feat, nullptr, 32768, 256, 512);
  ln_kernel<<<dim3(8192), 256, 0, stream>>>(rf_, ln1w, ln1b, yf_, 32768);
  gemm_kernel<1, bf16, bf16, bf16><<<dim3(256, 2), 256, 0, stream>>>(
      yf_, f1W1T, tf_, nullptr, nullptr, 32768, 256, 256);
  gemm_kernel<3, float, bf16, bf16><<<dim3(256, 2), 256, 0, stream>>>(
      tf_, f1W2T, out_feat, yf_, f1b2, 32768, 256, 256);

  // center path
  gemm_kernel<2, bf16, float, bf16><<<dim3(16, 2), 256, 0, stream>>>(
      acm_, Wo2T, rc_, center, nullptr, 2048, 256, 512);
  ln_kernel<<<dim3(512), 256, 0, stream>>>(rc_, ln2w, ln2b, yc_, 2048);
  gemm_kernel<1, bf16, bf16, bf16><<<dim3(16, 2), 256, 0, stream>>>(
      yc_, f2W1T, tc_, nullptr, nullptr, 2048, 256, 256);
  gemm_kernel<3, float, bf16, bf16><<<dim3(16, 2), 256, 0, stream>>>(
      tc_, f2W2T, out_center, yc_, f2b2, 2048, 256, 256);
}

// Round 4
// 387.318 us; speedup vs baseline: 1.1445x; 1.1445x over previous
//
#include <hip/hip_runtime.h>

typedef __bf16 bf16;
typedef __bf16 bf16x4 __attribute__((ext_vector_type(4)));
typedef __bf16 bf16x8 __attribute__((ext_vector_type(8)));
typedef float f32x4 __attribute__((ext_vector_type(4)));

#define MFMA16(a, b, c) __builtin_amdgcn_mfma_f32_16x16x32_bf16(a, b, c, 0, 0, 0)

// Problem constants: B=8, N=4096, M=256, DIM=256, HEADS=8, DIM_HEAD=64, INNER=512
// exp(S*scale) = exp2(S * 0.125 * log2(e))
#define CEXP 0.18033688011112042f

// ---------------------------------------------------------------------------
// Weight pre-transpose + downcast: W[K,N] fp32 -> WT[N,K] bf16 (10 matrices)
// ---------------------------------------------------------------------------
struct WTArgs {
  const float* src[10];
  bf16* dst[10];
  int K[10];
  int N[10];
};

__global__ __launch_bounds__(256) void wtrans_kernel(WTArgs args) {
  const int z = blockIdx.z;
  const int K = args.K[z], N = args.N[z];
  const int k0 = blockIdx.x * 64, n0 = blockIdx.y * 64;
  if (k0 >= K || n0 >= N) return;
  __shared__ float t[64][65];
  const int tx = threadIdx.x & 63, ty = threadIdx.x >> 6;
  const float* __restrict__ src = args.src[z];
  bf16* __restrict__ dst = args.dst[z];
#pragma unroll
  for (int i = 0; i < 16; ++i)
    t[ty + i * 4][tx] = src[(size_t)(k0 + ty + i * 4) * N + n0 + tx];
  __syncthreads();
#pragma unroll
  for (int i = 0; i < 16; ++i)
    dst[(size_t)(n0 + ty + i * 4) * K + k0 + tx] = (bf16)t[tx][ty + i * 4];
}

// ---------------------------------------------------------------------------
// xq[b][n][c] = feat[b][n][c] + pos[b][c][n]  (fp32 in, bf16 out)
// ---------------------------------------------------------------------------
__global__ __launch_bounds__(256) void prep_xq_kernel(
    const float* __restrict__ feat, const float* __restrict__ pos,
    bf16* __restrict__ xq) {
  const int n0 = blockIdx.x * 64;
  const int c0 = blockIdx.y * 64;
  const int b = blockIdx.z;
  __shared__ float t[64][65];
  const int tx = threadIdx.x & 63, ty = threadIdx.x >> 6;
#pragma unroll
  for (int i = 0; i < 16; ++i) {
    int c = ty + i * 4;
    t[c][tx] = pos[((size_t)b * 256 + c0 + c) * 4096 + n0 + tx];
  }
  __syncthreads();
#pragma unroll
  for (int i = 0; i < 16; ++i) {
    int n = ty + i * 4;
    size_t off = ((size_t)b * 4096 + n0 + n) * 256 + c0 + tx;
    xq[off] = (bf16)(feat[off] + t[tx][n]);
  }
}

// xk = center + center_pos (fp32 in, bf16 out, vectorized x4)
__global__ __launch_bounds__(256) void addvec_kernel(
    const float* __restrict__ a, const float* __restrict__ b,
    bf16* __restrict__ o, int n4) {
  int i = blockIdx.x * 256 + threadIdx.x;
  if (i < n4) {
    f32x4 x = ((const f32x4*)a)[i];
    f32x4 y = ((const f32x4*)b)[i];
    bf16x4 z;
#pragma unroll
    for (int j = 0; j < 4; ++j) z[j] = (bf16)(x[j] + y[j]);
    ((bf16x4*)o)[i] = z;
  }
}

// ---------------------------------------------------------------------------
// GEMM staging helpers. bf16 source: async DMA global->LDS (16B/lane, linear
// dest). fp32 source: reg load + convert, SAME linear dest (content already
// source-swizzled by the caller, so layouts are identical).
// ---------------------------------------------------------------------------
__device__ inline void stage16(const bf16* g, bf16* l) {
  __builtin_amdgcn_global_load_lds(
      (const __attribute__((address_space(1))) void*)g,
      (__attribute__((address_space(3))) void*)l, 16, 0, 0);
}
__device__ inline void stage16(const float* g, bf16* l) {
  f32x4 u = *(const f32x4*)g;
  f32x4 v = *((const f32x4*)g + 1);
  bf16x8 o;
#pragma unroll
  for (int i = 0; i < 4; ++i) {
    o[i] = (bf16)u[i];
    o[4 + i] = (bf16)v[i];
  }
  *(bf16x8*)l = o;
}

// ---------------------------------------------------------------------------
// Generic GEMM: C[M,N] = A[M,K] @ B[K,N], B pre-transposed BT[N,K] (bf16).
// 128x128 tile, 4 waves (each 64x64), BK=32, single-buffered LDS.
// Staging via global_load_lds(16B): LDS dest is lane-linear (rule #21), the
// per-lane GLOBAL source granule is XOR-swizzled (g ^ (row>>1)&3, involution)
// and fragment reads apply the same XOR -> 8 words/bank floor, no pad.
// EPI: 0=none, 1=relu, 2=+resid, 3=+bias+resid. TO out, TR resid, TA a-input.
// ---------------------------------------------------------------------------
template <int EPI, typename TO, typename TR, typename TA>
__global__ __launch_bounds__(256) void gemm_kernel(
    const TA* __restrict__ A, const bf16* __restrict__ BT,
    TO* __restrict__ C, const TR* __restrict__ resid,
    const float* __restrict__ bias, int M, int N, int K) {
  const int m0 = blockIdx.x * 128;
  const int n0 = blockIdx.y * 128;
  const int tid = threadIdx.x;
  const int lane = tid & 63;
  const int w = tid >> 6;
  const int wr = (w >> 1) * 64, wc = (w & 1) * 64;
  const int l15 = lane & 15, quad = lane >> 4;

  __shared__ __align__(16) bf16 Al[128 * 32];  // 8KB, no pad (DMA dest)
  __shared__ __align__(16) bf16 Bl[128 * 32];

  f32x4 acc[4][4];
#pragma unroll
  for (int i = 0; i < 4; ++i)
#pragma unroll
    for (int j = 0; j < 4; ++j) acc[i][j] = (f32x4){0.f, 0.f, 0.f, 0.f};

  const int sw = (((l15 >> 1) & 3) ^ quad) * 8;  // read-side swizzled granule

  for (int k0 = 0; k0 < K; k0 += 32) {
#pragma unroll
    for (int c = 0; c < 2; ++c) {
      int idx = tid + c * 256;                    // 0..511
      int row = idx >> 2;                         // 0..127
      int gs = ((idx & 3) ^ ((row >> 1) & 3)) * 8;  // source granule (elems)
      stage16(A + (size_t)(m0 + row) * K + k0 + gs, Al + idx * 8);
      stage16(BT + (size_t)(n0 + row) * K + k0 + gs, Bl + idx * 8);
    }
    __syncthreads();
    bf16x8 fa[4], fb[4];
#pragma unroll
    for (int i = 0; i < 4; ++i) {
      fa[i] = *(const bf16x8*)(Al + (wr + i * 16 + l15) * 32 + sw);
      fb[i] = *(const bf16x8*)(Bl + (wc + i * 16 + l15) * 32 + sw);
    }
#pragma unroll
    for (int i = 0; i < 4; ++i)
#pragma unroll
      for (int j = 0; j < 4; ++j)
        acc[i][j] = MFMA16(fa[i], fb[j], acc[i][j]);
    __syncthreads();
  }

#pragma unroll
  for (int i = 0; i < 4; ++i) {
#pragma unroll
    for (int r = 0; r < 4; ++r) {
      int row = m0 + wr + i * 16 + quad * 4 + r;
      size_t rb = (size_t)row * N + n0 + wc;
#pragma unroll
      for (int j = 0; j < 4; ++j) {
        int col = j * 16 + l15;
        float v = acc[i][j][r];
        if constexpr (EPI == 1) v = fmaxf(v, 0.f);
        if constexpr (EPI == 2) v += (float)resid[rb + col];
        if constexpr (EPI == 3)
          v += bias[n0 + wc + col] + (float)resid[rb + col];
        C[rb + col] = (TO)v;
      }
    }
  }
}

// ---------------------------------------------------------------------------
// Fused dual-softmax attention (round-1 verified version, 99.6us).
// Grid (nb=4, h=8, b=8): each block owns 1024 n-rows of one (b,h).
//   - K [256][72] and v2T [64][264] staged ONCE per block (156KB LDS total,
//     1 block/CU by design).
//   - 16 ch-chunks of 64 rows; per ch only v1T (double-buffered, register-
//     prefetched one chunk ahead) is staged -> 2 barriers per ch.
//   - Outputs are atomic-free: per-block partial acc/colsum slabs indexed by
//     nb; acm_kernel sums the 4 partials.
// Per ch: E[n,m]=exp(q.k/8) once, feeding O1 = rownorm(E) @ v2 (af out) and
// O2 += E^T @ v1 (acc partial), colsum += sum_n E.
// NOTE: af aliases q (same rows read-before-write per block; all cross-block
// row/col slices disjoint) -> q/af intentionally NOT __restrict__.
// ---------------------------------------------------------------------------
__global__ __launch_bounds__(256, 1) void attf_kernel(
    const bf16* q, const bf16* __restrict__ kk, const bf16* __restrict__ v1,
    const bf16* __restrict__ v2, bf16* af, float* __restrict__ acc_p,
    float* __restrict__ colsum_p) {
  const int nb = blockIdx.x;  // 4 blocks of 1024 rows
  const int h = blockIdx.y;
  const int b = blockIdx.z;
  const int tid = threadIdx.x;
  const int lane = tid & 63;
  const int w = tid >> 6;
  const int l15 = lane & 15, quad = lane >> 4;

  __shared__ __align__(16) bf16 klds[256 * 72];   // [m][d]        36.0 KB
  __shared__ __align__(16) bf16 v2T[64 * 264];    // [d][m]        33.0 KB
  __shared__ __align__(16) bf16 v1T[2][64 * 72];  // [d][n_local]  18.0 KB
  __shared__ __align__(16) bf16 PT[256 * 72];     // [m][n_local]  36.0 KB
  __shared__ __align__(16) bf16 Pl[4][16 * 264];  // per-wave P    33.0 KB

  // ---- prologue: stage K and v2T once, v1T[0], q frags for ch=0 ----
#pragma unroll
  for (int c = 0; c < 8; ++c) {
    int idx = tid + c * 256;  // 0..2047
    int m = idx >> 3;
    int dc = (idx & 7) * 8;
    *(bf16x8*)(klds + m * 72 + dc) =
        *(const bf16x8*)(kk + ((size_t)(b * 256 + m)) * 512 + h * 64 + dc);
  }
#pragma unroll
  for (int c = 0; c < 8; ++c) {
    int idx = tid + c * 256;
    int m = idx >> 3;
    int dc = (idx & 7) * 8;
    bf16x8 t =
        *(const bf16x8*)(v2 + ((size_t)(b * 256 + m)) * 512 + h * 64 + dc);
#pragma unroll
    for (int j = 0; j < 8; ++j) v2T[(dc + j) * 264 + m] = t[j];
  }
  {
    const int nl = tid >> 3;
    const int dc = (tid & 7) * 8;
    const bf16* v1b =
        v1 + ((size_t)(b * 4096 + nb * 1024)) * 512 + h * 64 + dc;
    bf16x8 t0 = *(const bf16x8*)(v1b + (size_t)nl * 512);
    bf16x8 t1 = *(const bf16x8*)(v1b + (size_t)(nl + 32) * 512);
#pragma unroll
    for (int j = 0; j < 8; ++j) {
      v1T[0][(dc + j) * 72 + nl] = t0[j];
      v1T[0][(dc + j) * 72 + nl + 32] = t1[j];
    }
  }
  // q fragments for this wave's 16 rows of ch=0
  bf16x8 qa0, qa1;
  {
    int nrow = b * 4096 + nb * 1024 + w * 16 + l15;
    const bf16* qp = q + (size_t)nrow * 512 + h * 64 + quad * 8;
    qa0 = *(const bf16x8*)(qp);
    qa1 = *(const bf16x8*)(qp + 32);
  }

  f32x4 oc2[16];
#pragma unroll
  for (int i = 0; i < 16; ++i) oc2[i] = (f32x4){0.f, 0.f, 0.f, 0.f};
  float cs[16];
#pragma unroll
  for (int i = 0; i < 16; ++i) cs[i] = 0.f;

  __syncthreads();

#pragma unroll 2
  for (int ch = 0; ch < 16; ++ch) {
    // ---------------- phase A: QK^T + O1 + af ----------------
    // v1(ch+1) global->reg prefetch (latency hides under QK compute)
    bf16x8 v1a, v1b;
    const int nl = tid >> 3;
    const int dc = (tid & 7) * 8;
    if (ch < 15) {
      const bf16* v1p =
          v1 + ((size_t)(b * 4096 + nb * 1024 + (ch + 1) * 64)) * 512 +
          h * 64 + dc;
      v1a = *(const bf16x8*)(v1p + (size_t)nl * 512);
      v1b = *(const bf16x8*)(v1p + (size_t)(nl + 32) * 512);
    }

    float rs[4] = {0.f, 0.f, 0.f, 0.f};
#pragma unroll
    for (int mt = 0; mt < 16; ++mt) {
      const bf16* kp = klds + (mt * 16 + l15) * 72 + quad * 8;
      bf16x8 b0 = *(const bf16x8*)(kp);
      bf16x8 b1 = *(const bf16x8*)(kp + 32);
      f32x4 s = (f32x4){0.f, 0.f, 0.f, 0.f};
      s = MFMA16(qa0, b0, s);
      s = MFMA16(qa1, b1, s);
      float e0 = exp2f(s[0] * CEXP);
      float e1 = exp2f(s[1] * CEXP);
      float e2 = exp2f(s[2] * CEXP);
      float e3 = exp2f(s[3] * CEXP);
      rs[0] += e0; rs[1] += e1; rs[2] += e2; rs[3] += e3;
      cs[mt] += e0 + e1 + e2 + e3;
      Pl[w][(quad * 4 + 0) * 264 + mt * 16 + l15] = (bf16)e0;
      Pl[w][(quad * 4 + 1) * 264 + mt * 16 + l15] = (bf16)e1;
      Pl[w][(quad * 4 + 2) * 264 + mt * 16 + l15] = (bf16)e2;
      Pl[w][(quad * 4 + 3) * 264 + mt * 16 + l15] = (bf16)e3;
      bf16x4 ev;
      ev[0] = (bf16)e0; ev[1] = (bf16)e1; ev[2] = (bf16)e2; ev[3] = (bf16)e3;
      *(bf16x4*)(PT + (mt * 16 + l15) * 72 + w * 16 + quad * 4) = ev;
    }
    // write prefetched v1 into the other buffer (read at ch+1's O phase)
    if (ch < 15) {
      bf16* dst = v1T[(ch + 1) & 1];
#pragma unroll
      for (int j = 0; j < 8; ++j) {
        dst[(dc + j) * 72 + nl] = v1a[j];
        dst[(dc + j) * 72 + nl + 32] = v1b[j];
      }
    }
    __syncthreads();  // Pl/PT (+next v1T) ready

    // ---------------- phase B ----------------
    // prefetch q fragments for ch+1 (af writes below touch different rows)
    bf16x8 qn0 = qa0, qn1 = qa1;
    if (ch < 15) {
      int nrow = b * 4096 + nb * 1024 + (ch + 1) * 64 + w * 16 + l15;
      const bf16* qp = q + (size_t)nrow * 512 + h * 64 + quad * 8;
      qn0 = *(const bf16x8*)(qp);
      qn1 = *(const bf16x8*)(qp + 32);
    }

    // O1 = P @ v2  (k = m, 8 ksteps of 32)
    f32x4 o1[4];
#pragma unroll
    for (int i = 0; i < 4; ++i) o1[i] = (f32x4){0.f, 0.f, 0.f, 0.f};
#pragma unroll
    for (int ks = 0; ks < 8; ++ks) {
      bf16x8 pa = *(const bf16x8*)(Pl[w] + l15 * 264 + ks * 32 + quad * 8);
#pragma unroll
      for (int dt = 0; dt < 4; ++dt) {
        bf16x8 vb = *(const bf16x8*)(v2T + (dt * 16 + l15) * 264 + ks * 32 +
                                     quad * 8);
        o1[dt] = MFMA16(pa, vb, o1[dt]);
      }
    }
    // rowsum reduce over the 16 m-columns held across l15 lanes
    float inv[4];
#pragma unroll
    for (int r = 0; r < 4; ++r) {
      float v = rs[r];
      v += __shfl_xor(v, 1, 64);
      v += __shfl_xor(v, 2, 64);
      v += __shfl_xor(v, 4, 64);
      v += __shfl_xor(v, 8, 64);
      inv[r] = 1.f / v;
    }
    // write normalized O1 rows (af aliases q; these rows were read at QK(ch))
#pragma unroll
    for (int dt = 0; dt < 4; ++dt) {
#pragma unroll
      for (int r = 0; r < 4; ++r) {
        int n = nb * 1024 + ch * 64 + w * 16 + quad * 4 + r;
        af[((size_t)(b * 4096 + n)) * 512 + h * 64 + dt * 16 + l15] =
            (bf16)(o1[dt][r] * inv[r]);
      }
    }

    // O2 += E^T @ v1  (k = n_local 64 -> 2 ksteps; wave owns m-stripe per mq)
    const bf16* vc = v1T[ch & 1];
#pragma unroll
    for (int ks = 0; ks < 2; ++ks) {
      bf16x8 vbv[4];
#pragma unroll
      for (int dt = 0; dt < 4; ++dt)
        vbv[dt] = *(const bf16x8*)(vc + (dt * 16 + l15) * 72 + ks * 32 +
                                   quad * 8);
#pragma unroll
      for (int mq = 0; mq < 4; ++mq) {
        bf16x8 pa2 = *(const bf16x8*)(PT + (mq * 64 + w * 16 + l15) * 72 +
                                      ks * 32 + quad * 8);
#pragma unroll
        for (int dt = 0; dt < 4; ++dt)
          oc2[mq * 4 + dt] = MFMA16(pa2, vbv[dt], oc2[mq * 4 + dt]);
      }
    }
    __syncthreads();  // WAR: Pl/PT/v1T reads done before next ch restage
    qa0 = qn0;
    qa1 = qn1;
  }

  // ---- epilogue (atomic-free): per-block partial slabs indexed by nb ----
  // colsum: reduce over quads, then across waves via LDS (klds is dead)
  float* cw = (float*)klds;  // 4 waves x 256 floats
#pragma unroll
  for (int t = 0; t < 16; ++t) {
    float v = cs[t];
    v += __shfl_xor(v, 16, 64);
    v += __shfl_xor(v, 32, 64);
    if (quad == 0) cw[w * 256 + t * 16 + l15] = v;
  }
  __syncthreads();
  {
    int m = tid;
    float s = cw[m] + cw[256 + m] + cw[512 + m] + cw[768 + m];
    colsum_p[((size_t)(nb * 64 + b * 8 + h)) * 256 + m] = s;
  }
  // O2 partial: plain stores, block owns the whole (nb,b,h) slab
  float* base = acc_p + ((size_t)(nb * 64 + b * 8 + h)) * 256 * 64;
#pragma unroll
  for (int mq = 0; mq < 4; ++mq) {
#pragma unroll
    for (int dt = 0; dt < 4; ++dt) {
#pragma unroll
      for (int r = 0; r < 4; ++r) {
        int m = mq * 64 + w * 16 + quad * 4 + r;
        base[m * 64 + dt * 16 + l15] = oc2[mq * 4 + dt][r];
      }
    }
  }
}

// ---------------------------------------------------------------------------
// acm[b][m][h*64+d] = sum_p acc_p[p][b][h][m][d] / sum_p colsum_p[p][b][h][m]
// ---------------------------------------------------------------------------
__global__ __launch_bounds__(256) void acm_kernel(
    const float* __restrict__ acc_p, const float* __restrict__ colsum_p,
    bf16* __restrict__ acm) {
  int idx = blockIdx.x * 256 + threadIdx.x;  // 8*256*512 total
  int d = idx & 63;
  int h = (idx >> 6) & 7;
  int m = (idx >> 9) & 255;
  int b = idx >> 17;
  float cv = 0.f, v = 0.f;
#pragma unroll
  for (int p = 0; p < 4; ++p) {
    cv += colsum_p[((size_t)(p * 64 + b * 8 + h)) * 256 + m];
    v += acc_p[(((size_t)(p * 64 + b * 8 + h)) * 256 + m) * 64 + d];
  }
  acm[idx] = (bf16)(v / cv);
}

// ---------------------------------------------------------------------------
// LayerNorm over last dim (256): one wave per row, 4 rows per block.
// ---------------------------------------------------------------------------
__global__ __launch_bounds__(256) void ln_kernel(
    const bf16* __restrict__ x, const float* __restrict__ wv,
    const float* __restrict__ bv, bf16* __restrict__ y, int rows) {
  int wave = threadIdx.x >> 6;
  int lane = threadIdx.x & 63;
  int row = blockIdx.x * 4 + wave;
  if (row >= rows) return;
  const bf16* xr = x + (size_t)row * 256;
  bf16x4 v = *(const bf16x4*)(xr + lane * 4);
  float f0 = v[0], f1 = v[1], f2 = v[2], f3 = v[3];
  float s = f0 + f1 + f2 + f3;
  float ss = f0 * f0 + f1 * f1 + f2 * f2 + f3 * f3;
#pragma unroll
  for (int m = 1; m < 64; m <<= 1) {
    s += __shfl_xor(s, m, 64);
    ss += __shfl_xor(ss, m, 64);
  }
  float mean = s * (1.f / 256.f);
  float var = ss * (1.f / 256.f) - mean * mean;
  float rstd = rsqrtf(var + 1e-5f);
  f32x4 wq = *(const f32x4*)(wv + lane * 4);
  f32x4 bq = *(const f32x4*)(bv + lane * 4);
  bf16x4 o;
  o[0] = (bf16)((f0 - mean) * rstd * wq[0] + bq[0]);
  o[1] = (bf16)((f1 - mean) * rstd * wq[1] + bq[1]);
  o[2] = (bf16)((f2 - mean) * rstd * wq[2] + bq[2]);
  o[3] = (bf16)((f3 - mean) * rstd * wq[3] + bq[3]);
  *(bf16x4*)(y + (size_t)row * 256 + lane * 4) = o;
}

// ---------------------------------------------------------------------------
extern "C" void kernel_launch(void* const* d_in, const int* in_sizes, int n_in,
                              void* d_out, int out_size, void* d_ws,
                              size_t ws_size, hipStream_t stream) {
  const float* feat = (const float*)d_in[0];
  const float* center = (const float*)d_in[1];
  const float* pos = (const float*)d_in[2];
  const float* cpos = (const float*)d_in[3];
  const float* Wq = (const float*)d_in[4];
  const float* Wk = (const float*)d_in[5];
  const float* Wv1 = (const float*)d_in[6];
  const float* Wv2 = (const float*)d_in[7];
  const float* Wo1 = (const float*)d_in[8];
  const float* Wo2 = (const float*)d_in[9];
  const float* ln1w = (const float*)d_in[10];
  const float* ln1b = (const float*)d_in[11];
  const float* ln2w = (const float*)d_in[12];
  const float* ln2b = (const float*)d_in[13];
  const float* f1W1 = (const float*)d_in[14];
  const float* f1W2 = (const float*)d_in[15];
  const float* f1b2 = (const float*)d_in[16];
  const float* f2W1 = (const float*)d_in[17];
  const float* f2W2 = (const float*)d_in[18];
  const float* f2b2 = (const float*)d_in[19];

  char* ws = (char*)d_ws;
  const size_t MB = 1024 * 1024;
  // workspace layout (~94 MB). af aliases q (fused kernel reads q rows before
  // writing the same rows). acc partials alias xq (dead after q GEMM); acm
  // aliases v2 (dead after attf).
  bf16* q_ = (bf16*)(ws + 0);           // 32MB [32768,512]
  bf16* af_ = q_;                       // alias (see attf_kernel note)
  bf16* v1_ = (bf16*)(ws + 32 * MB);    // 32MB [32768,512]
  bf16* xq_ = (bf16*)(ws + 64 * MB);    // 16MB [32768,256]
  float* accp_ = (float*)(ws + 64 * MB);  // alias: 16MB fp32 [4,8,8,256,64]
  bf16* rf_ = xq_;                      // alias after acm (Wo1 GEMM output)
  bf16* k_ = (bf16*)(ws + 80 * MB);     // 2MB [2048,512]
  bf16* xk_ = (bf16*)(ws + 82 * MB);    // 1MB [2048,256]
  bf16* rc_ = xk_;                      // alias
  bf16* v2_ = (bf16*)(ws + 83 * MB);    // 2MB [2048,512]
  bf16* acm_ = v2_;                     // alias after attf
  float* colsum_ = (float*)(ws + 89 * MB);     // 256KB fp32 [4,8,8,256]
  bf16* wt_ = (bf16*)(ws + 89 * MB + 262144);  // 2MB transposed weights
  bf16* yf_ = q_;                       // alias: af dead after Wo1 GEMM
  bf16* tf_ = (bf16*)(ws + 16 * MB);    // upper half of q/af region
  bf16* yc_ = (bf16*)(ws + 92 * MB);    // 1MB
  bf16* tc_ = (bf16*)(ws + 93 * MB);    // 1MB

  bf16* WqT = wt_;
  bf16* WkT = WqT + 131072;
  bf16* Wv1T = WkT + 131072;
  bf16* Wv2T = Wv1T + 131072;
  bf16* Wo1T = Wv2T + 131072;
  bf16* Wo2T = Wo1T + 131072;
  bf16* f1W1T = Wo2T + 131072;
  bf16* f1W2T = f1W1T + 65536;
  bf16* f2W1T = f1W2T + 65536;
  bf16* f2W2T = f2W1T + 65536;

  float* out_feat = (float*)d_out;
  float* out_center = out_feat + (size_t)8 * 4096 * 256;

  WTArgs wa;
  const float* srcs[10] = {Wq, Wk, Wv1, Wv2, Wo1, Wo2, f1W1, f1W2, f2W1, f2W2};
  bf16* dsts[10] = {WqT, WkT, Wv1T, Wv2T, Wo1T, Wo2T, f1W1T, f1W2T, f2W1T, f2W2T};
  int Ks[10] = {256, 256, 256, 256, 512, 512, 256, 256, 256, 256};
  int Ns[10] = {512, 512, 512, 512, 256, 256, 256, 256, 256, 256};
  for (int i = 0; i < 10; ++i) {
    wa.src[i] = srcs[i];
    wa.dst[i] = dsts[i];
    wa.K[i] = Ks[i];
    wa.N[i] = Ns[i];
  }

  wtrans_kernel<<<dim3(8, 8, 10), 256, 0, stream>>>(wa);
  prep_xq_kernel<<<dim3(64, 4, 8), 256, 0, stream>>>(feat, pos, xq_);
  addvec_kernel<<<dim3(512), 256, 0, stream>>>(center, cpos, xk_, 131072);

  // projections (v1/v2 read fp32 inputs directly via reg-staging path)
  gemm_kernel<0, bf16, bf16, bf16><<<dim3(256, 4), 256, 0, stream>>>(
      xq_, WqT, q_, nullptr, nullptr, 32768, 512, 256);
  gemm_kernel<0, bf16, bf16, bf16><<<dim3(16, 4), 256, 0, stream>>>(
      xk_, WkT, k_, nullptr, nullptr, 2048, 512, 256);
  gemm_kernel<0, bf16, bf16, float><<<dim3(256, 4), 256, 0, stream>>>(
      feat, Wv1T, v1_, nullptr, nullptr, 32768, 512, 256);
  gemm_kernel<0, bf16, bf16, float><<<dim3(16, 4), 256, 0, stream>>>(
      center, Wv2T, v2_, nullptr, nullptr, 2048, 512, 256);

  // fused dual-softmax attention (atomic-free partials, no memset needed)
  attf_kernel<<<dim3(4, 8, 8), 256, 0, stream>>>(q_, k_, v1_, v2_, af_, accp_,
                                                 colsum_);
  acm_kernel<<<dim3(4096), 256, 0, stream>>>(accp_, colsum_, acm_);

  // feat path
  gemm_kernel<2, bf16, float, bf16><<<dim3(256, 2), 256, 0, stream>>>(
      af_, Wo1T, rf_, feat, nullptr, 32768, 256, 512);
  ln_kernel<<<dim3(8192), 256, 0, stream>>>(rf_, ln1w, ln1b, yf_, 32768);
  gemm_kernel<1, bf16, bf16, bf16><<<dim3(256, 2), 256, 0, stream>>>(
      yf_, f1W1T, tf_, nullptr, nullptr, 32768, 256, 256);
  gemm_kernel<3, float, bf16, bf16><<<dim3(256, 2), 256, 0, stream>>>(
      tf_, f1W2T, out_feat, yf_, f1b2, 32768, 256, 256);

  // center path
  gemm_kernel<2, bf16, float, bf16><<<dim3(16, 2), 256, 0, stream>>>(
      acm_, Wo2T, rc_, center, nullptr, 2048, 256, 512);
  ln_kernel<<<dim3(512), 256, 0, stream>>>(rc_, ln2w, ln2b, yc_, 2048);
  gemm_kernel<1, bf16, bf16, bf16><<<dim3(16, 2), 256, 0, stream>>>(
      yc_, f2W1T, tc_, nullptr, nullptr, 2048, 256, 256);
  gemm_kernel<3, float, bf16, bf16><<<dim3(16, 2), 256, 0, stream>>>(
      tc_, f2W2T, out_center, yc_, f2b2, 2048, 256, 256);
}

// Round 5
// 379.639 us; speedup vs baseline: 1.1677x; 1.0202x over previous
//
#include <hip/hip_runtime.h>

typedef __bf16 bf16;
typedef __bf16 bf16x4 __attribute__((ext_vector_type(4)));
typedef __bf16 bf16x8 __attribute__((ext_vector_type(8)));
typedef float f32x4 __attribute__((ext_vector_type(4)));

#define MFMA16(a, b, c) __builtin_amdgcn_mfma_f32_16x16x32_bf16(a, b, c, 0, 0, 0)

// Problem constants: B=8, N=4096, M=256, DIM=256, HEADS=8, DIM_HEAD=64, INNER=512
// exp(S*scale) = exp2(S * 0.125 * log2(e))
#define CEXP 0.18033688011112042f

// ---------------------------------------------------------------------------
// Weight pre-transpose + downcast: W[K,N] fp32 -> WT[N,K] bf16 (10 matrices)
// ---------------------------------------------------------------------------
struct WTArgs {
  const float* src[10];
  bf16* dst[10];
  int K[10];
  int N[10];
};

__global__ __launch_bounds__(256) void wtrans_kernel(WTArgs args) {
  const int z = blockIdx.z;
  const int K = args.K[z], N = args.N[z];
  const int k0 = blockIdx.x * 64, n0 = blockIdx.y * 64;
  if (k0 >= K || n0 >= N) return;
  __shared__ float t[64][65];
  const int tx = threadIdx.x & 63, ty = threadIdx.x >> 6;
  const float* __restrict__ src = args.src[z];
  bf16* __restrict__ dst = args.dst[z];
#pragma unroll
  for (int i = 0; i < 16; ++i)
    t[ty + i * 4][tx] = src[(size_t)(k0 + ty + i * 4) * N + n0 + tx];
  __syncthreads();
#pragma unroll
  for (int i = 0; i < 16; ++i)
    dst[(size_t)(n0 + ty + i * 4) * K + k0 + tx] = (bf16)t[tx][ty + i * 4];
}

// ---------------------------------------------------------------------------
// xq[b][n][c] = feat[b][n][c] + pos[b][c][n]  (fp32 in, bf16 out)
// ---------------------------------------------------------------------------
__global__ __launch_bounds__(256) void prep_xq_kernel(
    const float* __restrict__ feat, const float* __restrict__ pos,
    bf16* __restrict__ xq) {
  const int n0 = blockIdx.x * 64;
  const int c0 = blockIdx.y * 64;
  const int b = blockIdx.z;
  __shared__ float t[64][65];
  const int tx = threadIdx.x & 63, ty = threadIdx.x >> 6;
#pragma unroll
  for (int i = 0; i < 16; ++i) {
    int c = ty + i * 4;
    t[c][tx] = pos[((size_t)b * 256 + c0 + c) * 4096 + n0 + tx];
  }
  __syncthreads();
#pragma unroll
  for (int i = 0; i < 16; ++i) {
    int n = ty + i * 4;
    size_t off = ((size_t)b * 4096 + n0 + n) * 256 + c0 + tx;
    xq[off] = (bf16)(feat[off] + t[tx][n]);
  }
}

// ---------------------------------------------------------------------------
// Staging helpers. bf16: async DMA global->LDS (16B/lane, linear dest).
// fp32: reg load + convert (optional fused add of a second fp32 source).
// ---------------------------------------------------------------------------
__device__ inline void stage16(const bf16* g, bf16* l) {
  __builtin_amdgcn_global_load_lds(
      (const __attribute__((address_space(1))) void*)g,
      (__attribute__((address_space(3))) void*)l, 16, 0, 0);
}
__device__ inline void stage16(const float* g, bf16* l) {
  f32x4 u = *(const f32x4*)g;
  f32x4 v = *((const f32x4*)g + 1);
  bf16x8 o;
#pragma unroll
  for (int i = 0; i < 4; ++i) {
    o[i] = (bf16)u[i];
    o[4 + i] = (bf16)v[i];
  }
  *(bf16x8*)l = o;
}
__device__ inline void stage16(const float* g, const float* g2, bf16* l) {
  f32x4 u = *(const f32x4*)g + *(const f32x4*)g2;
  f32x4 v = *((const f32x4*)g + 1) + *((const f32x4*)g2 + 1);
  bf16x8 o;
#pragma unroll
  for (int i = 0; i < 4; ++i) {
    o[i] = (bf16)u[i];
    o[4 + i] = (bf16)v[i];
  }
  *(bf16x8*)l = o;
}

// Epilogue helpers: vectorized resid load / C store.
__device__ inline f32x4 rload(const float* p) { return *(const f32x4*)p; }
__device__ inline f32x4 rload(const bf16* p) {
  bf16x4 t = *(const bf16x4*)p;
  return (f32x4){(float)t[0], (float)t[1], (float)t[2], (float)t[3]};
}
__device__ inline void cstore(float* p, f32x4 v) { *(f32x4*)p = v; }
__device__ inline void cstore(bf16* p, f32x4 v) {
  bf16x4 o;
  o[0] = (bf16)v[0]; o[1] = (bf16)v[1]; o[2] = (bf16)v[2]; o[3] = (bf16)v[3];
  *(bf16x4*)p = o;
}

// ---------------------------------------------------------------------------
// Generic GEMM, dual-problem batched via blockIdx.z (slot z; blocks beyond
// M[z] early-return). C[M,N] = A[M,K] @ B[K,N], B pre-transposed BT[N,K].
// 128x128 tile, 4 waves (each 64x64), BK=32, single-buffered LDS,
// global_load_lds staging (involution source-swizzle, rule #21).
// SWAPPED-OPERAND MFMA: acc holds C^T fragments -> each lane owns 4
// CONSECUTIVE output columns -> vectorized epilogue (8B/16B stores) with
// vectorized resid/bias loads. FUSE2: A-operand = A + A2 (fp32 only).
// EPI: 0=none, 1=relu, 2=+resid, 3=+bias+resid.
// ---------------------------------------------------------------------------
struct GArg {
  const void* A[2];
  const void* A2[2];
  const bf16* BT[2];
  void* C[2];
  const void* resid[2];
  const float* bias[2];
  int M[2];
};

template <int EPI, typename TO, typename TR, typename TA, bool FUSE2>
__global__ __launch_bounds__(256) void gemm_kernel(GArg g, int N, int K) {
  const int z = blockIdx.z;
  const int m0 = blockIdx.x * 128;
  if (m0 >= g.M[z]) return;
  const TA* A = (const TA*)g.A[z];
  const TA* A2 = (const TA*)g.A2[z];
  const bf16* BT = g.BT[z];
  TO* C = (TO*)g.C[z];
  const TR* resid = (const TR*)g.resid[z];
  const float* bias = g.bias[z];

  const int n0 = blockIdx.y * 128;
  const int tid = threadIdx.x;
  const int lane = tid & 63;
  const int w = tid >> 6;
  const int wr = (w >> 1) * 64, wc = (w & 1) * 64;
  const int l15 = lane & 15, quad = lane >> 4;

  __shared__ __align__(16) bf16 Al[128 * 32];  // 8KB, no pad (DMA dest)
  __shared__ __align__(16) bf16 Bl[128 * 32];

  f32x4 acc[4][4];
#pragma unroll
  for (int i = 0; i < 4; ++i)
#pragma unroll
    for (int j = 0; j < 4; ++j) acc[i][j] = (f32x4){0.f, 0.f, 0.f, 0.f};

  const int sw = (((l15 >> 1) & 3) ^ quad) * 8;  // read-side swizzled granule

  for (int k0 = 0; k0 < K; k0 += 32) {
#pragma unroll
    for (int c = 0; c < 2; ++c) {
      int idx = tid + c * 256;                      // 0..511
      int row = idx >> 2;                           // 0..127
      int gs = ((idx & 3) ^ ((row >> 1) & 3)) * 8;  // source granule (elems)
      size_t aoff = (size_t)(m0 + row) * K + k0 + gs;
      if constexpr (FUSE2)
        stage16(A + aoff, A2 + aoff, Al + idx * 8);
      else
        stage16(A + aoff, Al + idx * 8);
      stage16(BT + (size_t)(n0 + row) * K + k0 + gs, Bl + idx * 8);
    }
    __syncthreads();
    bf16x8 fa[4], fb[4];
#pragma unroll
    for (int i = 0; i < 4; ++i) {
      fa[i] = *(const bf16x8*)(Al + (wr + i * 16 + l15) * 32 + sw);
      fb[i] = *(const bf16x8*)(Bl + (wc + i * 16 + l15) * 32 + sw);
    }
#pragma unroll
    for (int i = 0; i < 4; ++i)
#pragma unroll
      for (int j = 0; j < 4; ++j)
        acc[i][j] = MFMA16(fb[j], fa[i], acc[i][j]);  // swapped: acc = C^T frag
    __syncthreads();
  }

  // Epilogue: lane holds rows row=l15-based, 4 consecutive cols.
#pragma unroll
  for (int i = 0; i < 4; ++i) {
#pragma unroll
    for (int j = 0; j < 4; ++j) {
      int row = m0 + wr + i * 16 + l15;
      int col = n0 + wc + j * 16 + quad * 4;
      size_t off = (size_t)row * N + col;
      f32x4 v = acc[i][j];
      if constexpr (EPI == 1) {
#pragma unroll
        for (int e = 0; e < 4; ++e) v[e] = fmaxf(v[e], 0.f);
      }
      if constexpr (EPI == 2) v += rload(resid + off);
      if constexpr (EPI == 3)
        v += rload(resid + off) + *(const f32x4*)(bias + col);
      cstore(C + off, v);
    }
  }
}

// ---------------------------------------------------------------------------
// Fused dual-softmax attention (round-1 verified structure, 99.6us) with
// swapped-operand O1/O2 MFMAs for vectorized af / acc_p stores.
// Grid (nb=4, h=8, b=8): each block owns 1024 n-rows of one (b,h).
// K [256][72] + v2T [64][264] staged once (156KB LDS, 1 block/CU).
// 16 ch-chunks of 64 rows; 2 barriers per ch; v1 double-buffered with
// global->reg prefetch; q prefetched in phase B.
// NOTE: af aliases q (same rows read-before-write) -> NOT __restrict__.
// ---------------------------------------------------------------------------
__global__ __launch_bounds__(256, 1) void attf_kernel(
    const bf16* q, const bf16* __restrict__ kk, const bf16* __restrict__ v1,
    const bf16* __restrict__ v2, bf16* af, float* __restrict__ acc_p,
    float* __restrict__ colsum_p) {
  const int nb = blockIdx.x;  // 4 blocks of 1024 rows
  const int h = blockIdx.y;
  const int b = blockIdx.z;
  const int tid = threadIdx.x;
  const int lane = tid & 63;
  const int w = tid >> 6;
  const int l15 = lane & 15, quad = lane >> 4;

  __shared__ __align__(16) bf16 klds[256 * 72];   // [m][d]        36.0 KB
  __shared__ __align__(16) bf16 v2T[64 * 264];    // [d][m]        33.0 KB
  __shared__ __align__(16) bf16 v1T[2][64 * 72];  // [d][n_local]  18.0 KB
  __shared__ __align__(16) bf16 PT[256 * 72];     // [m][n_local]  36.0 KB
  __shared__ __align__(16) bf16 Pl[4][16 * 264];  // per-wave P    33.0 KB

  // ---- prologue: stage K and v2T once, v1T[0], q frags for ch=0 ----
#pragma unroll
  for (int c = 0; c < 8; ++c) {
    int idx = tid + c * 256;  // 0..2047
    int m = idx >> 3;
    int dc = (idx & 7) * 8;
    *(bf16x8*)(klds + m * 72 + dc) =
        *(const bf16x8*)(kk + ((size_t)(b * 256 + m)) * 512 + h * 64 + dc);
  }
#pragma unroll
  for (int c = 0; c < 8; ++c) {
    int idx = tid + c * 256;
    int m = idx >> 3;
    int dc = (idx & 7) * 8;
    bf16x8 t =
        *(const bf16x8*)(v2 + ((size_t)(b * 256 + m)) * 512 + h * 64 + dc);
#pragma unroll
    for (int j = 0; j < 8; ++j) v2T[(dc + j) * 264 + m] = t[j];
  }
  {
    const int nl = tid >> 3;
    const int dc = (tid & 7) * 8;
    const bf16* v1b =
        v1 + ((size_t)(b * 4096 + nb * 1024)) * 512 + h * 64 + dc;
    bf16x8 t0 = *(const bf16x8*)(v1b + (size_t)nl * 512);
    bf16x8 t1 = *(const bf16x8*)(v1b + (size_t)(nl + 32) * 512);
#pragma unroll
    for (int j = 0; j < 8; ++j) {
      v1T[0][(dc + j) * 72 + nl] = t0[j];
      v1T[0][(dc + j) * 72 + nl + 32] = t1[j];
    }
  }
  // q fragments for this wave's 16 rows of ch=0
  bf16x8 qa0, qa1;
  {
    int nrow = b * 4096 + nb * 1024 + w * 16 + l15;
    const bf16* qp = q + (size_t)nrow * 512 + h * 64 + quad * 8;
    qa0 = *(const bf16x8*)(qp);
    qa1 = *(const bf16x8*)(qp + 32);
  }

  f32x4 oc2[16];
#pragma unroll
  for (int i = 0; i < 16; ++i) oc2[i] = (f32x4){0.f, 0.f, 0.f, 0.f};
  float cs[16];
#pragma unroll
  for (int i = 0; i < 16; ++i) cs[i] = 0.f;

  __syncthreads();

#pragma unroll 2
  for (int ch = 0; ch < 16; ++ch) {
    // ---------------- phase A: QK^T ----------------
    // v1(ch+1) global->reg prefetch (latency hides under QK compute)
    bf16x8 v1a, v1b;
    const int nl = tid >> 3;
    const int dc = (tid & 7) * 8;
    if (ch < 15) {
      const bf16* v1p =
          v1 + ((size_t)(b * 4096 + nb * 1024 + (ch + 1) * 64)) * 512 +
          h * 64 + dc;
      v1a = *(const bf16x8*)(v1p + (size_t)nl * 512);
      v1b = *(const bf16x8*)(v1p + (size_t)(nl + 32) * 512);
    }

    float rs[4] = {0.f, 0.f, 0.f, 0.f};
#pragma unroll
    for (int mt = 0; mt < 16; ++mt) {
      const bf16* kp = klds + (mt * 16 + l15) * 72 + quad * 8;
      bf16x8 b0 = *(const bf16x8*)(kp);
      bf16x8 b1 = *(const bf16x8*)(kp + 32);
      f32x4 s = (f32x4){0.f, 0.f, 0.f, 0.f};
      s = MFMA16(qa0, b0, s);
      s = MFMA16(qa1, b1, s);
      float e0 = exp2f(s[0] * CEXP);
      float e1 = exp2f(s[1] * CEXP);
      float e2 = exp2f(s[2] * CEXP);
      float e3 = exp2f(s[3] * CEXP);
      rs[0] += e0; rs[1] += e1; rs[2] += e2; rs[3] += e3;
      cs[mt] += e0 + e1 + e2 + e3;
      Pl[w][(quad * 4 + 0) * 264 + mt * 16 + l15] = (bf16)e0;
      Pl[w][(quad * 4 + 1) * 264 + mt * 16 + l15] = (bf16)e1;
      Pl[w][(quad * 4 + 2) * 264 + mt * 16 + l15] = (bf16)e2;
      Pl[w][(quad * 4 + 3) * 264 + mt * 16 + l15] = (bf16)e3;
      bf16x4 ev;
      ev[0] = (bf16)e0; ev[1] = (bf16)e1; ev[2] = (bf16)e2; ev[3] = (bf16)e3;
      *(bf16x4*)(PT + (mt * 16 + l15) * 72 + w * 16 + quad * 4) = ev;
    }
    // write prefetched v1 into the other buffer (read at ch+1's O phase)
    if (ch < 15) {
      bf16* dst = v1T[(ch + 1) & 1];
#pragma unroll
      for (int j = 0; j < 8; ++j) {
        dst[(dc + j) * 72 + nl] = v1a[j];
        dst[(dc + j) * 72 + nl + 32] = v1b[j];
      }
    }
    __syncthreads();  // Pl/PT (+next v1T) ready

    // ---------------- phase B ----------------
    // prefetch q fragments for ch+1 (af writes below touch different rows)
    bf16x8 qn0 = qa0, qn1 = qa1;
    if (ch < 15) {
      int nrow = b * 4096 + nb * 1024 + (ch + 1) * 64 + w * 16 + l15;
      const bf16* qp = q + (size_t)nrow * 512 + h * 64 + quad * 8;
      qn0 = *(const bf16x8*)(qp);
      qn1 = *(const bf16x8*)(qp + 32);
    }

    // O1 = P @ v2 (SWAPPED: lane holds [n=l15][4 consecutive d])
    f32x4 o1[4];
#pragma unroll
    for (int i = 0; i < 4; ++i) o1[i] = (f32x4){0.f, 0.f, 0.f, 0.f};
#pragma unroll
    for (int ks = 0; ks < 8; ++ks) {
      bf16x8 pa = *(const bf16x8*)(Pl[w] + l15 * 264 + ks * 32 + quad * 8);
#pragma unroll
      for (int dt = 0; dt < 4; ++dt) {
        bf16x8 vb = *(const bf16x8*)(v2T + (dt * 16 + l15) * 264 + ks * 32 +
                                     quad * 8);
        o1[dt] = MFMA16(vb, pa, o1[dt]);
      }
    }
    // rowsum: reduce over l15, then fetch own row (l15) across quads
#pragma unroll
    for (int r = 0; r < 4; ++r) {
      float v = rs[r];
      v += __shfl_xor(v, 1, 64);
      v += __shfl_xor(v, 2, 64);
      v += __shfl_xor(v, 4, 64);
      v += __shfl_xor(v, 8, 64);
      rs[r] = v;
    }
    {
      int srcq = (l15 >> 2) << 4;
      float s0 = __shfl(rs[0], srcq, 64);
      float s1 = __shfl(rs[1], srcq, 64);
      float s2 = __shfl(rs[2], srcq, 64);
      float s3 = __shfl(rs[3], srcq, 64);
      float a01 = (l15 & 1) ? s1 : s0;
      float a23 = (l15 & 1) ? s3 : s2;
      float inv = 1.f / ((l15 & 2) ? a23 : a01);
      // vectorized af write: row n = ..+l15, cols d = dt*16 + quad*4 + e
      int n = nb * 1024 + ch * 64 + w * 16 + l15;
      bf16* ap = af + ((size_t)(b * 4096 + n)) * 512 + h * 64 + quad * 4;
#pragma unroll
      for (int dt = 0; dt < 4; ++dt) {
        bf16x4 ov;
        ov[0] = (bf16)(o1[dt][0] * inv);
        ov[1] = (bf16)(o1[dt][1] * inv);
        ov[2] = (bf16)(o1[dt][2] * inv);
        ov[3] = (bf16)(o1[dt][3] * inv);
        *(bf16x4*)(ap + dt * 16) = ov;
      }
    }

    // O2 += E^T @ v1 (SWAPPED: lane holds [m=..+l15][4 consecutive d])
    const bf16* vc = v1T[ch & 1];
#pragma unroll
    for (int ks = 0; ks < 2; ++ks) {
      bf16x8 vbv[4];
#pragma unroll
      for (int dt = 0; dt < 4; ++dt)
        vbv[dt] = *(const bf16x8*)(vc + (dt * 16 + l15) * 72 + ks * 32 +
                                   quad * 8);
#pragma unroll
      for (int mq = 0; mq < 4; ++mq) {
        bf16x8 pa2 = *(const bf16x8*)(PT + (mq * 64 + w * 16 + l15) * 72 +
                                      ks * 32 + quad * 8);
#pragma unroll
        for (int dt = 0; dt < 4; ++dt)
          oc2[mq * 4 + dt] = MFMA16(vbv[dt], pa2, oc2[mq * 4 + dt]);
      }
    }
    __syncthreads();  // WAR: Pl/PT/v1T reads done before next ch restage
    qa0 = qn0;
    qa1 = qn1;
  }

  // ---- epilogue (atomic-free): per-block partial slabs indexed by nb ----
  // colsum: reduce over quads, then across waves via LDS (klds is dead)
  float* cw = (float*)klds;  // 4 waves x 256 floats
#pragma unroll
  for (int t = 0; t < 16; ++t) {
    float v = cs[t];
    v += __shfl_xor(v, 16, 64);
    v += __shfl_xor(v, 32, 64);
    if (quad == 0) cw[w * 256 + t * 16 + l15] = v;
  }
  __syncthreads();
  {
    int m = tid;
    float s = cw[m] + cw[256 + m] + cw[512 + m] + cw[768 + m];
    colsum_p[((size_t)(nb * 64 + b * 8 + h)) * 256 + m] = s;
  }
  // O2 partial: vectorized stores, block owns the whole (nb,b,h) slab
  float* base = acc_p + ((size_t)(nb * 64 + b * 8 + h)) * 256 * 64;
#pragma unroll
  for (int mq = 0; mq < 4; ++mq) {
    int m = mq * 64 + w * 16 + l15;
#pragma unroll
    for (int dt = 0; dt < 4; ++dt)
      *(f32x4*)(base + m * 64 + dt * 16 + quad * 4) = oc2[mq * 4 + dt];
  }
}

// ---------------------------------------------------------------------------
// acm[b][m][h*64+d] = sum_p acc_p[p][b][h][m][d] / sum_p colsum_p[p][b][h][m]
// ---------------------------------------------------------------------------
__global__ __launch_bounds__(256) void acm_kernel(
    const float* __restrict__ acc_p, const float* __restrict__ colsum_p,
    bf16* __restrict__ acm) {
  int idx = blockIdx.x * 256 + threadIdx.x;  // 8*256*512 total
  int d = idx & 63;
  int h = (idx >> 6) & 7;
  int m = (idx >> 9) & 255;
  int b = idx >> 17;
  float cv = 0.f, v = 0.f;
#pragma unroll
  for (int p = 0; p < 4; ++p) {
    cv += colsum_p[((size_t)(p * 64 + b * 8 + h)) * 256 + m];
    v += acc_p[(((size_t)(p * 64 + b * 8 + h)) * 256 + m) * 64 + d];
  }
  acm[idx] = (bf16)(v / cv);
}

// ---------------------------------------------------------------------------
// LayerNorm over last dim (256), dual-problem batched by row range.
// ---------------------------------------------------------------------------
__global__ __launch_bounds__(256) void ln_kernel(
    const bf16* __restrict__ x0, const bf16* __restrict__ x1,
    const float* __restrict__ w0, const float* __restrict__ b0,
    const float* __restrict__ w1, const float* __restrict__ b1,
    bf16* __restrict__ y0, bf16* __restrict__ y1, int rows0, int rows1) {
  int wave = threadIdx.x >> 6;
  int lane = threadIdx.x & 63;
  int row = blockIdx.x * 4 + wave;
  const bf16* x;
  const float *wv, *bv;
  bf16* y;
  if (row < rows0) {
    x = x0; wv = w0; bv = b0; y = y0;
  } else {
    row -= rows0;
    if (row >= rows1) return;
    x = x1; wv = w1; bv = b1; y = y1;
  }
  const bf16* xr = x + (size_t)row * 256;
  bf16x4 v = *(const bf16x4*)(xr + lane * 4);
  float f0 = v[0], f1 = v[1], f2 = v[2], f3 = v[3];
  float s = f0 + f1 + f2 + f3;
  float ss = f0 * f0 + f1 * f1 + f2 * f2 + f3 * f3;
#pragma unroll
  for (int m = 1; m < 64; m <<= 1) {
    s += __shfl_xor(s, m, 64);
    ss += __shfl_xor(ss, m, 64);
  }
  float mean = s * (1.f / 256.f);
  float var = ss * (1.f / 256.f) - mean * mean;
  float rstd = rsqrtf(var + 1e-5f);
  f32x4 wq = *(const f32x4*)(wv + lane * 4);
  f32x4 bq = *(const f32x4*)(bv + lane * 4);
  bf16x4 o;
  o[0] = (bf16)((f0 - mean) * rstd * wq[0] + bq[0]);
  o[1] = (bf16)((f1 - mean) * rstd * wq[1] + bq[1]);
  o[2] = (bf16)((f2 - mean) * rstd * wq[2] + bq[2]);
  o[3] = (bf16)((f3 - mean) * rstd * wq[3] + bq[3]);
  *(bf16x4*)(y + (size_t)row * 256 + lane * 4) = o;
}

// ---------------------------------------------------------------------------
extern "C" void kernel_launch(void* const* d_in, const int* in_sizes, int n_in,
                              void* d_out, int out_size, void* d_ws,
                              size_t ws_size, hipStream_t stream) {
  const float* feat = (const float*)d_in[0];
  const float* center = (const float*)d_in[1];
  const float* pos = (const float*)d_in[2];
  const float* cpos = (const float*)d_in[3];
  const float* Wq = (const float*)d_in[4];
  const float* Wk = (const float*)d_in[5];
  const float* Wv1 = (const float*)d_in[6];
  const float* Wv2 = (const float*)d_in[7];
  const float* Wo1 = (const float*)d_in[8];
  const float* Wo2 = (const float*)d_in[9];
  const float* ln1w = (const float*)d_in[10];
  const float* ln1b = (const float*)d_in[11];
  const float* ln2w = (const float*)d_in[12];
  const float* ln2b = (const float*)d_in[13];
  const float* f1W1 = (const float*)d_in[14];
  const float* f1W2 = (const float*)d_in[15];
  const float* f1b2 = (const float*)d_in[16];
  const float* f2W1 = (const float*)d_in[17];
  const float* f2W2 = (const float*)d_in[18];
  const float* f2b2 = (const float*)d_in[19];

  char* ws = (char*)d_ws;
  const size_t MB = 1024 * 1024;
  // workspace layout (~94 MB). af aliases q; acc partials alias xq (dead
  // after q GEMM); acm aliases v2 (dead after attf).
  bf16* q_ = (bf16*)(ws + 0);           // 32MB [32768,512]
  bf16* af_ = q_;                       // alias (see attf_kernel note)
  bf16* v1_ = (bf16*)(ws + 32 * MB);    // 32MB [32768,512]
  bf16* xq_ = (bf16*)(ws + 64 * MB);    // 16MB [32768,256]
  float* accp_ = (float*)(ws + 64 * MB);  // alias: 16MB fp32 [4,8,8,256,64]
  bf16* rf_ = xq_;                      // alias after acm (Wo1 GEMM output)
  bf16* k_ = (bf16*)(ws + 80 * MB);     // 2MB [2048,512]
  bf16* rc_ = (bf16*)(ws + 82 * MB);    // 1MB [2048,256]
  bf16* v2_ = (bf16*)(ws + 83 * MB);    // 2MB [2048,512]
  bf16* acm_ = v2_;                     // alias after attf
  float* colsum_ = (float*)(ws + 89 * MB);     // 256KB fp32 [4,8,8,256]
  bf16* wt_ = (bf16*)(ws + 89 * MB + 262144);  // 2MB transposed weights
  bf16* yf_ = q_;                       // alias: af dead after Wo1 GEMM
  bf16* tf_ = (bf16*)(ws + 16 * MB);    // upper half of q/af region
  bf16* yc_ = (bf16*)(ws + 92 * MB);    // 1MB
  bf16* tc_ = (bf16*)(ws + 93 * MB);    // 1MB

  bf16* WqT = wt_;
  bf16* WkT = WqT + 131072;
  bf16* Wv1T = WkT + 131072;
  bf16* Wv2T = Wv1T + 131072;
  bf16* Wo1T = Wv2T + 131072;
  bf16* Wo2T = Wo1T + 131072;
  bf16* f1W1T = Wo2T + 131072;
  bf16* f1W2T = f1W1T + 65536;
  bf16* f2W1T = f1W2T + 65536;
  bf16* f2W2T = f2W1T + 65536;

  float* out_feat = (float*)d_out;
  float* out_center = out_feat + (size_t)8 * 4096 * 256;

  WTArgs wa;
  const float* srcs[10] = {Wq, Wk, Wv1, Wv2, Wo1, Wo2, f1W1, f1W2, f2W1, f2W2};
  bf16* dsts[10] = {WqT, WkT, Wv1T, Wv2T, Wo1T, Wo2T, f1W1T, f1W2T, f2W1T, f2W2T};
  int Ks[10] = {256, 256, 256, 256, 512, 512, 256, 256, 256, 256};
  int Ns[10] = {512, 512, 512, 512, 256, 256, 256, 256, 256, 256};
  for (int i = 0; i < 10; ++i) {
    wa.src[i] = srcs[i];
    wa.dst[i] = dsts[i];
    wa.K[i] = Ks[i];
    wa.N[i] = Ns[i];
  }

  wtrans_kernel<<<dim3(8, 8, 10), 256, 0, stream>>>(wa);
  prep_xq_kernel<<<dim3(64, 4, 8), 256, 0, stream>>>(feat, pos, xq_);

  // q projection
  {
    GArg a{};
    a.A[0] = xq_; a.BT[0] = WqT; a.C[0] = q_; a.M[0] = 32768;
    gemm_kernel<0, bf16, bf16, bf16, false>
        <<<dim3(256, 4, 1), 256, 0, stream>>>(a, 512, 256);
  }
  // k projection with fused (center + cpos) add
  {
    GArg a{};
    a.A[0] = center; a.A2[0] = cpos; a.BT[0] = WkT; a.C[0] = k_;
    a.M[0] = 2048;
    gemm_kernel<0, bf16, bf16, float, true>
        <<<dim3(16, 4, 1), 256, 0, stream>>>(a, 512, 256);
  }
  // v1 + v2 projections (batched, fp32 A)
  {
    GArg a{};
    a.A[0] = feat; a.A[1] = center;
    a.BT[0] = Wv1T; a.BT[1] = Wv2T;
    a.C[0] = v1_; a.C[1] = v2_;
    a.M[0] = 32768; a.M[1] = 2048;
    gemm_kernel<0, bf16, bf16, float, false>
        <<<dim3(256, 4, 2), 256, 0, stream>>>(a, 512, 256);
  }

  // fused dual-softmax attention (atomic-free partials)
  attf_kernel<<<dim3(4, 8, 8), 256, 0, stream>>>(q_, k_, v1_, v2_, af_, accp_,
                                                 colsum_);
  acm_kernel<<<dim3(4096), 256, 0, stream>>>(accp_, colsum_, acm_);

  // Wo1 + Wo2 (batched, +resid)
  {
    GArg a{};
    a.A[0] = af_; a.A[1] = acm_;
    a.BT[0] = Wo1T; a.BT[1] = Wo2T;
    a.C[0] = rf_; a.C[1] = rc_;
    a.resid[0] = feat; a.resid[1] = center;
    a.M[0] = 32768; a.M[1] = 2048;
    gemm_kernel<2, bf16, float, bf16, false>
        <<<dim3(256, 2, 2), 256, 0, stream>>>(a, 256, 512);
  }
  // ln1 + ln2 (batched)
  ln_kernel<<<dim3(8704), 256, 0, stream>>>(rf_, rc_, ln1w, ln1b, ln2w, ln2b,
                                            yf_, yc_, 32768, 2048);
  // FFN W1 (relu) batched
  {
    GArg a{};
    a.A[0] = yf_; a.A[1] = yc_;
    a.BT[0] = f1W1T; a.BT[1] = f2W1T;
    a.C[0] = tf_; a.C[1] = tc_;
    a.M[0] = 32768; a.M[1] = 2048;
    gemm_kernel<1, bf16, bf16, bf16, false>
        <<<dim3(256, 2, 2), 256, 0, stream>>>(a, 256, 256);
  }
  // FFN W2 (+bias+resid, fp32 out) batched
  {
    GArg a{};
    a.A[0] = tf_; a.A[1] = tc_;
    a.BT[0] = f1W2T; a.BT[1] = f2W2T;
    a.C[0] = out_feat; a.C[1] = out_center;
    a.resid[0] = yf_; a.resid[1] = yc_;
    a.bias[0] = f1b2; a.bias[1] = f2b2;
    a.M[0] = 32768; a.M[1] = 2048;
    gemm_kernel<3, float, bf16, bf16, false>
        <<<dim3(256, 2, 2), 256, 0, stream>>>(a, 256, 256);
  }
}

// Round 6
// 359.212 us; speedup vs baseline: 1.2341x; 1.0569x over previous
//
#include <hip/hip_runtime.h>

typedef __bf16 bf16;
typedef __bf16 bf16x4 __attribute__((ext_vector_type(4)));
typedef __bf16 bf16x8 __attribute__((ext_vector_type(8)));
typedef float f32x4 __attribute__((ext_vector_type(4)));

#define MFMA16(a, b, c) __builtin_amdgcn_mfma_f32_16x16x32_bf16(a, b, c, 0, 0, 0)

// Problem constants: B=8, N=4096, M=256, DIM=256, HEADS=8, DIM_HEAD=64, INNER=512
// exp(S*scale) = exp2(S * 0.125 * log2(e))
#define CEXP 0.18033688011112042f

// ---------------------------------------------------------------------------
// Weight pre-transpose + downcast: W[K,N] fp32 -> WT[N,K] bf16 (10 matrices)
// ---------------------------------------------------------------------------
struct WTArgs {
  const float* src[10];
  bf16* dst[10];
  int K[10];
  int N[10];
};

__global__ __launch_bounds__(256) void wtrans_kernel(WTArgs args) {
  const int z = blockIdx.z;
  const int K = args.K[z], N = args.N[z];
  const int k0 = blockIdx.x * 64, n0 = blockIdx.y * 64;
  if (k0 >= K || n0 >= N) return;
  __shared__ float t[64][65];
  const int tx = threadIdx.x & 63, ty = threadIdx.x >> 6;
  const float* __restrict__ src = args.src[z];
  bf16* __restrict__ dst = args.dst[z];
#pragma unroll
  for (int i = 0; i < 16; ++i)
    t[ty + i * 4][tx] = src[(size_t)(k0 + ty + i * 4) * N + n0 + tx];
  __syncthreads();
#pragma unroll
  for (int i = 0; i < 16; ++i)
    dst[(size_t)(n0 + ty + i * 4) * K + k0 + tx] = (bf16)t[tx][ty + i * 4];
}

// ---------------------------------------------------------------------------
// xq[b][n][c] = feat[b][n][c] + pos[b][c][n]  (fp32 in, bf16 out)
// ---------------------------------------------------------------------------
__global__ __launch_bounds__(256) void prep_xq_kernel(
    const float* __restrict__ feat, const float* __restrict__ pos,
    bf16* __restrict__ xq) {
  const int n0 = blockIdx.x * 64;
  const int c0 = blockIdx.y * 64;
  const int b = blockIdx.z;
  __shared__ float t[64][65];
  const int tx = threadIdx.x & 63, ty = threadIdx.x >> 6;
#pragma unroll
  for (int i = 0; i < 16; ++i) {
    int c = ty + i * 4;
    t[c][tx] = pos[((size_t)b * 256 + c0 + c) * 4096 + n0 + tx];
  }
  __syncthreads();
#pragma unroll
  for (int i = 0; i < 16; ++i) {
    int n = ty + i * 4;
    size_t off = ((size_t)b * 4096 + n0 + n) * 256 + c0 + tx;
    xq[off] = (bf16)(feat[off] + t[tx][n]);
  }
}

// ---------------------------------------------------------------------------
// Staging helpers. bf16: async DMA global->LDS (16B/lane, linear dest).
// fp32: reg load + convert (optional fused add of a second fp32 source).
// ---------------------------------------------------------------------------
__device__ inline void stage16(const bf16* g, bf16* l) {
  __builtin_amdgcn_global_load_lds(
      (const __attribute__((address_space(1))) void*)g,
      (__attribute__((address_space(3))) void*)l, 16, 0, 0);
}
__device__ inline void stage16(const float* g, bf16* l) {
  f32x4 u = *(const f32x4*)g;
  f32x4 v = *((const f32x4*)g + 1);
  bf16x8 o;
#pragma unroll
  for (int i = 0; i < 4; ++i) {
    o[i] = (bf16)u[i];
    o[4 + i] = (bf16)v[i];
  }
  *(bf16x8*)l = o;
}
__device__ inline void stage16(const float* g, const float* g2, bf16* l) {
  f32x4 u = *(const f32x4*)g + *(const f32x4*)g2;
  f32x4 v = *((const f32x4*)g + 1) + *((const f32x4*)g2 + 1);
  bf16x8 o;
#pragma unroll
  for (int i = 0; i < 4; ++i) {
    o[i] = (bf16)u[i];
    o[4 + i] = (bf16)v[i];
  }
  *(bf16x8*)l = o;
}

// Epilogue helpers: vectorized resid load / C store.
__device__ inline f32x4 rload(const float* p) { return *(const f32x4*)p; }
__device__ inline f32x4 rload(const bf16* p) {
  bf16x4 t = *(const bf16x4*)p;
  return (f32x4){(float)t[0], (float)t[1], (float)t[2], (float)t[3]};
}
__device__ inline void cstore(float* p, f32x4 v) { *(f32x4*)p = v; }
__device__ inline void cstore(bf16* p, f32x4 v) {
  bf16x4 o;
  o[0] = (bf16)v[0]; o[1] = (bf16)v[1]; o[2] = (bf16)v[2]; o[3] = (bf16)v[3];
  *(bf16x4*)p = o;
}

// ---------------------------------------------------------------------------
// Generic GEMM, dual-problem batched via blockIdx.z. C[M,N] = A[M,K] @ B[K,N],
// B pre-transposed BT[N,K]. 128x128 tile, 4 waves, BK=32.
// DOUBLE-BUFFERED LDS, ONE barrier per K-step: barrier -> issue DMA for
// step t+1 -> ds_read+MFMA step t. The global->LDS latency hides under the
// current step's compute instead of being drained immediately (the
// stage->sync->compute pattern exposes full HBM latency every step).
// SWAPPED-OPERAND MFMA: acc holds C^T fragments -> lane owns 4 consecutive
// output columns -> vectorized epilogue. FUSE2: A-operand = A + A2 (fp32).
// EPI: 0=none, 1=relu, 2=+resid, 3=+bias+resid.
// ---------------------------------------------------------------------------
struct GArg {
  const void* A[2];
  const void* A2[2];
  const bf16* BT[2];
  void* C[2];
  const void* resid[2];
  const float* bias[2];
  int M[2];
};

template <int EPI, typename TO, typename TR, typename TA, bool FUSE2>
__global__ __launch_bounds__(256) void gemm_kernel(GArg g, int N, int K) {
  const int z = blockIdx.z;
  const int m0 = blockIdx.x * 128;
  if (m0 >= g.M[z]) return;
  const TA* A = (const TA*)g.A[z];
  const TA* A2 = (const TA*)g.A2[z];
  const bf16* BT = g.BT[z];
  TO* C = (TO*)g.C[z];
  const TR* resid = (const TR*)g.resid[z];
  const float* bias = g.bias[z];

  const int n0 = blockIdx.y * 128;
  const int tid = threadIdx.x;
  const int lane = tid & 63;
  const int w = tid >> 6;
  const int wr = (w >> 1) * 64, wc = (w & 1) * 64;
  const int l15 = lane & 15, quad = lane >> 4;

  __shared__ __align__(16) bf16 Al[2][128 * 32];  // 16KB (dbuf)
  __shared__ __align__(16) bf16 Bl[2][128 * 32];  // 16KB

  f32x4 acc[4][4];
#pragma unroll
  for (int i = 0; i < 4; ++i)
#pragma unroll
    for (int j = 0; j < 4; ++j) acc[i][j] = (f32x4){0.f, 0.f, 0.f, 0.f};

  const int sw = (((l15 >> 1) & 3) ^ quad) * 8;  // read-side swizzled granule

  auto stage = [&](int buf, int k0) {
#pragma unroll
    for (int c = 0; c < 2; ++c) {
      int idx = tid + c * 256;                      // 0..511
      int row = idx >> 2;                           // 0..127
      int gs = ((idx & 3) ^ ((row >> 1) & 3)) * 8;  // source granule (elems)
      size_t aoff = (size_t)(m0 + row) * K + k0 + gs;
      if constexpr (FUSE2)
        stage16(A + aoff, A2 + aoff, Al[buf] + idx * 8);
      else
        stage16(A + aoff, Al[buf] + idx * 8);
      stage16(BT + (size_t)(n0 + row) * K + k0 + gs, Bl[buf] + idx * 8);
    }
  };

  stage(0, 0);
  int cur = 0;
  const int nt = K >> 5;
  for (int t = 0; t < nt; ++t) {
    __syncthreads();  // buf[cur] staged (vmcnt drain) + WAR for buf[cur^1]
    if (t + 1 < nt) stage(cur ^ 1, (t + 1) * 32);  // flies under MFMA below
    bf16x8 fa[4], fb[4];
#pragma unroll
    for (int i = 0; i < 4; ++i) {
      fa[i] = *(const bf16x8*)(Al[cur] + (wr + i * 16 + l15) * 32 + sw);
      fb[i] = *(const bf16x8*)(Bl[cur] + (wc + i * 16 + l15) * 32 + sw);
    }
#pragma unroll
    for (int i = 0; i < 4; ++i)
#pragma unroll
      for (int j = 0; j < 4; ++j)
        acc[i][j] = MFMA16(fb[j], fa[i], acc[i][j]);  // swapped: C^T frags
    cur ^= 1;
  }

  // Epilogue: lane holds row=..+l15, 4 consecutive cols.
#pragma unroll
  for (int i = 0; i < 4; ++i) {
#pragma unroll
    for (int j = 0; j < 4; ++j) {
      int row = m0 + wr + i * 16 + l15;
      int col = n0 + wc + j * 16 + quad * 4;
      size_t off = (size_t)row * N + col;
      f32x4 v = acc[i][j];
      if constexpr (EPI == 1) {
#pragma unroll
        for (int e = 0; e < 4; ++e) v[e] = fmaxf(v[e], 0.f);
      }
      if constexpr (EPI == 2) v += rload(resid + off);
      if constexpr (EPI == 3)
        v += rload(resid + off) + *(const f32x4*)(bias + col);
      cstore(C + off, v);
    }
  }
}

// ---------------------------------------------------------------------------
// Fused dual-softmax attention. Round-1 structure (4 waves, 64-row chunks,
// full-K klds, 1 block/CU) + SWAPPED QK^T with register-held P:
//   s = mfma(K,q): lane (quad,l15) holds E[m=mt*16+quad*4+r][n=w*16+l15].
//   - O1's A-operand comes from REGISTERS (pa[8]); v2T columns carry the
//     fixed k-slot permutation pi (verified round 3) so A/B k-orders agree.
//   - Pl buffer + its conflicted stores GONE; rowsum is lane-local + 2
//     shuffles; colsum via ones-MFMA on PT (idle MFMA pipe, verified r3).
// LDS 123KB: klds [256][72] 36K | v2T [64][264] 33K | v1T[2][64][72] 18K |
//            PT [256][72] 36K.
// Outputs atomic-free per-block partial slabs (acm sums 4 partials).
// NOTE: af aliases q (same rows read-before-write) -> NOT __restrict__.
// ---------------------------------------------------------------------------
__global__ __launch_bounds__(256, 1) void attf_kernel(
    const bf16* q, const bf16* __restrict__ kk, const bf16* __restrict__ v1,
    const bf16* __restrict__ v2, bf16* af, float* __restrict__ acc_p,
    float* __restrict__ colsum_p) {
  const int nb = blockIdx.x;  // 4 blocks of 1024 rows
  const int h = blockIdx.y;
  const int b = blockIdx.z;
  const int tid = threadIdx.x;
  const int lane = tid & 63;
  const int w = tid >> 6;
  const int l15 = lane & 15, quad = lane >> 4;

  __shared__ __align__(16) bf16 klds[256 * 72];   // [m][d]        36.0 KB
  __shared__ __align__(16) bf16 v2T[64 * 264];    // [d][m-perm]   33.0 KB
  __shared__ __align__(16) bf16 v1T[2][64 * 72];  // [d][n_local]  18.0 KB
  __shared__ __align__(16) bf16 PT[256 * 72];     // [m][n_local]  36.0 KB

  // ---- prologue: stage K, v2T (perm'd cols), v1T[0]; q frags ch=0 ----
#pragma unroll
  for (int c = 0; c < 8; ++c) {
    int idx = tid + c * 256;  // 0..2047
    int m = idx >> 3;
    int dc = (idx & 7) * 8;
    *(bf16x8*)(klds + m * 72 + dc) =
        *(const bf16x8*)(kk + ((size_t)(b * 256 + m)) * 512 + h * 64 + dc);
  }
#pragma unroll
  for (int c = 0; c < 8; ++c) {
    int idx = tid + c * 256;
    int m = idx >> 3;
    int dc = (idx & 7) * 8;
    bf16x8 t =
        *(const bf16x8*)(v2 + ((size_t)(b * 256 + m)) * 512 + h * 64 + dc);
    // column position p = pi^-1(m): within 32-block, p = q4*8 + hi*4 + lo
    // (m = hi*16 + q4*4 + lo). Matches pa[] reg packing below (verified r3).
    int p = (m & ~31) |
            (((((m >> 2) & 3) << 3) + (m & 3)) + (((m >> 4) & 1) << 2));
#pragma unroll
    for (int j = 0; j < 8; ++j) v2T[(dc + j) * 264 + p] = t[j];
  }
  {
    const int nl = tid >> 3;
    const int dc = (tid & 7) * 8;
    const bf16* v1b =
        v1 + ((size_t)(b * 4096 + nb * 1024)) * 512 + h * 64 + dc;
    bf16x8 t0 = *(const bf16x8*)(v1b + (size_t)nl * 512);
    bf16x8 t1 = *(const bf16x8*)(v1b + (size_t)(nl + 32) * 512);
#pragma unroll
    for (int j = 0; j < 8; ++j) {
      v1T[0][(dc + j) * 72 + nl] = t0[j];
      v1T[0][(dc + j) * 72 + nl + 32] = t1[j];
    }
  }
  // q fragments for this wave's 16 rows of ch=0
  bf16x8 qa0, qa1;
  {
    int nrow = b * 4096 + nb * 1024 + w * 16 + l15;
    const bf16* qp = q + (size_t)nrow * 512 + h * 64 + quad * 8;
    qa0 = *(const bf16x8*)(qp);
    qa1 = *(const bf16x8*)(qp + 32);
  }

  f32x4 oc2[16];
#pragma unroll
  for (int i = 0; i < 16; ++i) oc2[i] = (f32x4){0.f, 0.f, 0.f, 0.f};
  f32x4 csa[4];
#pragma unroll
  for (int i = 0; i < 4; ++i) csa[i] = (f32x4){0.f, 0.f, 0.f, 0.f};
  bf16x8 ones8;
#pragma unroll
  for (int j = 0; j < 8; ++j) ones8[j] = (bf16)1.0f;

  __syncthreads();

  for (int ch = 0; ch < 16; ++ch) {
    // ---------------- phase A: QK^T (swapped) + O1 + af ----------------
    // v1(ch+1) global->reg prefetch (latency hides under QK compute)
    bf16x8 v1a, v1b;
    const int nl = tid >> 3;
    const int dc = (tid & 7) * 8;
    if (ch < 15) {
      const bf16* v1p =
          v1 + ((size_t)(b * 4096 + nb * 1024 + (ch + 1) * 64)) * 512 +
          h * 64 + dc;
      v1a = *(const bf16x8*)(v1p + (size_t)nl * 512);
      v1b = *(const bf16x8*)(v1p + (size_t)(nl + 32) * 512);
    }

    bf16x8 pa[8];
    float rs = 0.f;
#pragma unroll
    for (int mt = 0; mt < 16; ++mt) {
      const bf16* kp = klds + (mt * 16 + l15) * 72 + quad * 8;
      bf16x8 ka0 = *(const bf16x8*)(kp);
      bf16x8 ka1 = *(const bf16x8*)(kp + 32);
      f32x4 s = (f32x4){0.f, 0.f, 0.f, 0.f};
      s = MFMA16(ka0, qa0, s);  // swapped: A=K rows m, B=q cols n
      s = MFMA16(ka1, qa1, s);
      float e0 = exp2f(s[0] * CEXP);
      float e1 = exp2f(s[1] * CEXP);
      float e2 = exp2f(s[2] * CEXP);
      float e3 = exp2f(s[3] * CEXP);
      rs += (e0 + e1) + (e2 + e3);
      bf16 b0 = (bf16)e0, b1 = (bf16)e1, b2 = (bf16)e2, b3 = (bf16)e3;
      int mrow = mt * 16 + quad * 4;  // lane's E rows; col n = w*16+l15
      PT[(mrow + 0) * 72 + w * 16 + l15] = b0;
      PT[(mrow + 1) * 72 + w * 16 + l15] = b1;
      PT[(mrow + 2) * 72 + w * 16 + l15] = b2;
      PT[(mrow + 3) * 72 + w * 16 + l15] = b3;
      pa[mt >> 1][(mt & 1) * 4 + 0] = b0;
      pa[mt >> 1][(mt & 1) * 4 + 1] = b1;
      pa[mt >> 1][(mt & 1) * 4 + 2] = b2;
      pa[mt >> 1][(mt & 1) * 4 + 3] = b3;
    }

    // O1 = P @ v2 (A=v2T perm'd, B=pa from regs; lane->[n=l15][4 consec d])
    f32x4 o1[4];
#pragma unroll
    for (int i = 0; i < 4; ++i) o1[i] = (f32x4){0.f, 0.f, 0.f, 0.f};
#pragma unroll
    for (int ks = 0; ks < 8; ++ks) {
#pragma unroll
      for (int dt = 0; dt < 4; ++dt) {
        bf16x8 vb = *(const bf16x8*)(v2T + (dt * 16 + l15) * 264 + ks * 32 +
                                     quad * 8);
        o1[dt] = MFMA16(vb, pa[ks], o1[dt]);
      }
    }
    // rowsum: lane-local over m, + 2 cross-quad shuffles (same l15 = same n)
    {
      float rsf = rs + __shfl_xor(rs, 16, 64);
      rsf += __shfl_xor(rsf, 32, 64);
      float inv = 1.f / rsf;
      int n = nb * 1024 + ch * 64 + w * 16 + l15;
      bf16* ap = af + ((size_t)(b * 4096 + n)) * 512 + h * 64 + quad * 4;
#pragma unroll
      for (int dt = 0; dt < 4; ++dt) {
        bf16x4 ov;
        ov[0] = (bf16)(o1[dt][0] * inv);
        ov[1] = (bf16)(o1[dt][1] * inv);
        ov[2] = (bf16)(o1[dt][2] * inv);
        ov[3] = (bf16)(o1[dt][3] * inv);
        *(bf16x4*)(ap + dt * 16) = ov;
      }
    }

    // write prefetched v1 into the other buffer (read at ch+1's O2)
    if (ch < 15) {
      bf16* dst = v1T[(ch + 1) & 1];
#pragma unroll
      for (int j = 0; j < 8; ++j) {
        dst[(dc + j) * 72 + nl] = v1a[j];
        dst[(dc + j) * 72 + nl + 32] = v1b[j];
      }
    }
    __syncthreads();  // PT (+next v1T) ready

    // ---------------- phase B: O2 + colsum-MFMA ----------------
    // prefetch q fragments for ch+1 (af(ch) rows already written; disjoint)
    bf16x8 qn0 = qa0, qn1 = qa1;
    if (ch < 15) {
      int nrow = b * 4096 + nb * 1024 + (ch + 1) * 64 + w * 16 + l15;
      const bf16* qp = q + (size_t)nrow * 512 + h * 64 + quad * 8;
      qn0 = *(const bf16x8*)(qp);
      qn1 = *(const bf16x8*)(qp + 32);
    }

    const bf16* vc = v1T[ch & 1];
#pragma unroll
    for (int ks = 0; ks < 2; ++ks) {
      bf16x8 vbv[4];
#pragma unroll
      for (int dt = 0; dt < 4; ++dt)
        vbv[dt] = *(const bf16x8*)(vc + (dt * 16 + l15) * 72 + ks * 32 +
                                   quad * 8);
#pragma unroll
      for (int mq = 0; mq < 4; ++mq) {
        bf16x8 pa2 = *(const bf16x8*)(PT + (mq * 64 + w * 16 + l15) * 72 +
                                      ks * 32 + quad * 8);
#pragma unroll
        for (int dt = 0; dt < 4; ++dt)
          oc2[mq * 4 + dt] = MFMA16(vbv[dt], pa2, oc2[mq * 4 + dt]);
        csa[mq] = MFMA16(pa2, ones8, csa[mq]);  // colsum over n (ones-MFMA)
      }
    }
    __syncthreads();  // WAR: PT/v1T reads done before next ch restage
    qa0 = qn0;
    qa1 = qn1;
  }

  // ---- epilogue (atomic-free): per-block partial slabs indexed by nb ----
  const size_t slab = (size_t)(nb * 64 + b * 8 + h);
  if (l15 == 0) {
#pragma unroll
    for (int mq = 0; mq < 4; ++mq)
#pragma unroll
      for (int r = 0; r < 4; ++r)
        colsum_p[slab * 256 + mq * 64 + w * 16 + quad * 4 + r] = csa[mq][r];
  }
  float* base = acc_p + slab * (256 * 64);
#pragma unroll
  for (int mq = 0; mq < 4; ++mq) {
    int m = mq * 64 + w * 16 + l15;
#pragma unroll
    for (int dt = 0; dt < 4; ++dt)
      *(f32x4*)(base + m * 64 + dt * 16 + quad * 4) = oc2[mq * 4 + dt];
  }
}

// ---------------------------------------------------------------------------
// acm[b][m][h*64+d] = sum_p acc_p[p][b][h][m][d] / sum_p colsum_p[p][b][h][m]
// ---------------------------------------------------------------------------
__global__ __launch_bounds__(256) void acm_kernel(
    const float* __restrict__ acc_p, const float* __restrict__ colsum_p,
    bf16* __restrict__ acm) {
  int idx = blockIdx.x * 256 + threadIdx.x;  // 8*256*512 total
  int d = idx & 63;
  int h = (idx >> 6) & 7;
  int m = (idx >> 9) & 255;
  int b = idx >> 17;
  float cv = 0.f, v = 0.f;
#pragma unroll
  for (int p = 0; p < 4; ++p) {
    cv += colsum_p[((size_t)(p * 64 + b * 8 + h)) * 256 + m];
    v += acc_p[(((size_t)(p * 64 + b * 8 + h)) * 256 + m) * 64 + d];
  }
  acm[idx] = (bf16)(v / cv);
}

// ---------------------------------------------------------------------------
// LayerNorm over last dim (256), dual-problem batched by row range.
// ---------------------------------------------------------------------------
__global__ __launch_bounds__(256) void ln_kernel(
    const bf16* __restrict__ x0, const bf16* __restrict__ x1,
    const float* __restrict__ w0, const float* __restrict__ b0,
    const float* __restrict__ w1, const float* __restrict__ b1,
    bf16* __restrict__ y0, bf16* __restrict__ y1, int rows0, int rows1) {
  int wave = threadIdx.x >> 6;
  int lane = threadIdx.x & 63;
  int row = blockIdx.x * 4 + wave;
  const bf16* x;
  const float *wv, *bv;
  bf16* y;
  if (row < rows0) {
    x = x0; wv = w0; bv = b0; y = y0;
  } else {
    row -= rows0;
    if (row >= rows1) return;
    x = x1; wv = w1; bv = b1; y = y1;
  }
  const bf16* xr = x + (size_t)row * 256;
  bf16x4 v = *(const bf16x4*)(xr + lane * 4);
  float f0 = v[0], f1 = v[1], f2 = v[2], f3 = v[3];
  float s = f0 + f1 + f2 + f3;
  float ss = f0 * f0 + f1 * f1 + f2 * f2 + f3 * f3;
#pragma unroll
  for (int m = 1; m < 64; m <<= 1) {
    s += __shfl_xor(s, m, 64);
    ss += __shfl_xor(ss, m, 64);
  }
  float mean = s * (1.f / 256.f);
  float var = ss * (1.f / 256.f) - mean * mean;
  float rstd = rsqrtf(var + 1e-5f);
  f32x4 wq = *(const f32x4*)(wv + lane * 4);
  f32x4 bq = *(const f32x4*)(bv + lane * 4);
  bf16x4 o;
  o[0] = (bf16)((f0 - mean) * rstd * wq[0] + bq[0]);
  o[1] = (bf16)((f1 - mean) * rstd * wq[1] + bq[1]);
  o[2] = (bf16)((f2 - mean) * rstd * wq[2] + bq[2]);
  o[3] = (bf16)((f3 - mean) * rstd * wq[3] + bq[3]);
  *(bf16x4*)(y + (size_t)row * 256 + lane * 4) = o;
}

// ---------------------------------------------------------------------------
extern "C" void kernel_launch(void* const* d_in, const int* in_sizes, int n_in,
                              void* d_out, int out_size, void* d_ws,
                              size_t ws_size, hipStream_t stream) {
  const float* feat = (const float*)d_in[0];
  const float* center = (const float*)d_in[1];
  const float* pos = (const float*)d_in[2];
  const float* cpos = (const float*)d_in[3];
  const float* Wq = (const float*)d_in[4];
  const float* Wk = (const float*)d_in[5];
  const float* Wv1 = (const float*)d_in[6];
  const float* Wv2 = (const float*)d_in[7];
  const float* Wo1 = (const float*)d_in[8];
  const float* Wo2 = (const float*)d_in[9];
  const float* ln1w = (const float*)d_in[10];
  const float* ln1b = (const float*)d_in[11];
  const float* ln2w = (const float*)d_in[12];
  const float* ln2b = (const float*)d_in[13];
  const float* f1W1 = (const float*)d_in[14];
  const float* f1W2 = (const float*)d_in[15];
  const float* f1b2 = (const float*)d_in[16];
  const float* f2W1 = (const float*)d_in[17];
  const float* f2W2 = (const float*)d_in[18];
  const float* f2b2 = (const float*)d_in[19];

  char* ws = (char*)d_ws;
  const size_t MB = 1024 * 1024;
  // workspace layout (~94 MB). af aliases q; acc partials alias xq (dead
  // after q GEMM); acm aliases v2 (dead after attf).
  bf16* q_ = (bf16*)(ws + 0);           // 32MB [32768,512]
  bf16* af_ = q_;                       // alias (see attf_kernel note)
  bf16* v1_ = (bf16*)(ws + 32 * MB);    // 32MB [32768,512]
  bf16* xq_ = (bf16*)(ws + 64 * MB);    // 16MB [32768,256]
  float* accp_ = (float*)(ws + 64 * MB);  // alias: 16MB fp32 [4,8,8,256,64]
  bf16* rf_ = xq_;                      // alias after acm (Wo1 GEMM output)
  bf16* k_ = (bf16*)(ws + 80 * MB);     // 2MB [2048,512]
  bf16* rc_ = (bf16*)(ws + 82 * MB);    // 1MB [2048,256]
  bf16* v2_ = (bf16*)(ws + 83 * MB);    // 2MB [2048,512]
  bf16* acm_ = v2_;                     // alias after attf
  float* colsum_ = (float*)(ws + 89 * MB);     // 256KB fp32 [4,8,8,256]
  bf16* wt_ = (bf16*)(ws + 89 * MB + 262144);  // 2MB transposed weights
  bf16* yf_ = q_;                       // alias: af dead after Wo1 GEMM
  bf16* tf_ = (bf16*)(ws + 16 * MB);    // upper half of q/af region
  bf16* yc_ = (bf16*)(ws + 92 * MB);    // 1MB
  bf16* tc_ = (bf16*)(ws + 93 * MB);    // 1MB

  bf16* WqT = wt_;
  bf16* WkT = WqT + 131072;
  bf16* Wv1T = WkT + 131072;
  bf16* Wv2T = Wv1T + 131072;
  bf16* Wo1T = Wv2T + 131072;
  bf16* Wo2T = Wo1T + 131072;
  bf16* f1W1T = Wo2T + 131072;
  bf16* f1W2T = f1W1T + 65536;
  bf16* f2W1T = f1W2T + 65536;
  bf16* f2W2T = f2W1T + 65536;

  float* out_feat = (float*)d_out;
  float* out_center = out_feat + (size_t)8 * 4096 * 256;

  WTArgs wa;
  const float* srcs[10] = {Wq, Wk, Wv1, Wv2, Wo1, Wo2, f1W1, f1W2, f2W1, f2W2};
  bf16* dsts[10] = {WqT, WkT, Wv1T, Wv2T, Wo1T, Wo2T, f1W1T, f1W2T, f2W1T, f2W2T};
  int Ks[10] = {256, 256, 256, 256, 512, 512, 256, 256, 256, 256};
  int Ns[10] = {512, 512, 512, 512, 256, 256, 256, 256, 256, 256};
  for (int i = 0; i < 10; ++i) {
    wa.src[i] = srcs[i];
    wa.dst[i] = dsts[i];
    wa.K[i] = Ks[i];
    wa.N[i] = Ns[i];
  }

  wtrans_kernel<<<dim3(8, 8, 10), 256, 0, stream>>>(wa);
  prep_xq_kernel<<<dim3(64, 4, 8), 256, 0, stream>>>(feat, pos, xq_);

  // q projection
  {
    GArg a{};
    a.A[0] = xq_; a.BT[0] = WqT; a.C[0] = q_; a.M[0] = 32768;
    gemm_kernel<0, bf16, bf16, bf16, false>
        <<<dim3(256, 4, 1), 256, 0, stream>>>(a, 512, 256);
  }
  // k projection with fused (center + cpos) add
  {
    GArg a{};
    a.A[0] = center; a.A2[0] = cpos; a.BT[0] = WkT; a.C[0] = k_;
    a.M[0] = 2048;
    gemm_kernel<0, bf16, bf16, float, true>
        <<<dim3(16, 4, 1), 256, 0, stream>>>(a, 512, 256);
  }
  // v1 + v2 projections (batched, fp32 A)
  {
    GArg a{};
    a.A[0] = feat; a.A[1] = center;
    a.BT[0] = Wv1T; a.BT[1] = Wv2T;
    a.C[0] = v1_; a.C[1] = v2_;
    a.M[0] = 32768; a.M[1] = 2048;
    gemm_kernel<0, bf16, bf16, float, false>
        <<<dim3(256, 4, 2), 256, 0, stream>>>(a, 512, 256);
  }

  // fused dual-softmax attention (atomic-free partials)
  attf_kernel<<<dim3(4, 8, 8), 256, 0, stream>>>(q_, k_, v1_, v2_, af_, accp_,
                                                 colsum_);
  acm_kernel<<<dim3(4096), 256, 0, stream>>>(accp_, colsum_, acm_);

  // Wo1 + Wo2 (batched, +resid)
  {
    GArg a{};
    a.A[0] = af_; a.A[1] = acm_;
    a.BT[0] = Wo1T; a.BT[1] = Wo2T;
    a.C[0] = rf_; a.C[1] = rc_;
    a.resid[0] = feat; a.resid[1] = center;
    a.M[0] = 32768; a.M[1] = 2048;
    gemm_kernel<2, bf16, float, bf16, false>
        <<<dim3(256, 2, 2), 256, 0, stream>>>(a, 256, 512);
  }
  // ln1 + ln2 (batched)
  ln_kernel<<<dim3(8704), 256, 0, stream>>>(rf_, rc_, ln1w, ln1b, ln2w, ln2b,
                                            yf_, yc_, 32768, 2048);
  // FFN W1 (relu) batched
  {
    GArg a{};
    a.A[0] = yf_; a.A[1] = yc_;
    a.BT[0] = f1W1T; a.BT[1] = f2W1T;
    a.C[0] = tf_; a.C[1] = tc_;
    a.M[0] = 32768; a.M[1] = 2048;
    gemm_kernel<1, bf16, bf16, bf16, false>
        <<<dim3(256, 2, 2), 256, 0, stream>>>(a, 256, 256);
  }
  // FFN W2 (+bias+resid, fp32 out) batched
  {
    GArg a{};
    a.A[0] = tf_; a.A[1] = tc_;
    a.BT[0] = f1W2T; a.BT[1] = f2W2T;
    a.C[0] = out_feat; a.C[1] = out_center;
    a.resid[0] = yf_; a.resid[1] = yc_;
    a.bias[0] = f1b2; a.bias[1] = f2b2;
    a.M[0] = 32768; a.M[1] = 2048;
    gemm_kernel<3, float, bf16, bf16, false>
        <<<dim3(256, 2, 2), 256, 0, stream>>>(a, 256, 256);
  }
}